// Round 2
// baseline (546.584 us; speedup 1.0000x reference)
//
#include <hip/hip_runtime.h>
#include <math.h>

#define NC 32
#define NI 32
#define NL 50
#define NQ 36
#define ND 1024
#define LAMBDA 9.0f

#define BM 128
#define BN 128
#define BK 32

typedef __attribute__((ext_vector_type(8))) short bf16x8;
typedef __attribute__((ext_vector_type(4))) float floatx4;

static __device__ __forceinline__ unsigned short f2b(float f) {
    unsigned int u = __float_as_uint(f);
    unsigned int r = (u + 0x7fffu + ((u >> 16) & 1u)) >> 16;  // RNE
    return (unsigned short)r;
}
static __device__ __forceinline__ float bf2f(unsigned short u) {
    return __uint_as_float(((unsigned int)u) << 16);
}

// async global->LDS, 16B/lane; LDS dest must be wave-uniform base + lane*16
static __device__ __forceinline__ void gload16(const unsigned short* g, unsigned short* l) {
    __builtin_amdgcn_global_load_lds(
        (const __attribute__((address_space(1))) unsigned int*)g,
        (__attribute__((address_space(3))) unsigned int*)l, 16, 0, 0);
}

// ---------------------------------------------------------------------------
// K0a: fp32 -> bf16 (4 weights + zero-padded wrd)
// ---------------------------------------------------------------------------
struct CvtJob { const float* src; unsigned short* dst; int n2; int valid2; };
struct CvtJobs { CvtJob j[5]; };

__global__ __launch_bounds__(256) void k_cvt(CvtJobs jobs) {
    CvtJob jb = jobs.j[blockIdx.y];
    unsigned int* d32 = (unsigned int*)jb.dst;
    int stride = gridDim.x * 256;
    for (int i = blockIdx.x * 256 + threadIdx.x; i < jb.n2; i += stride) {
        unsigned int pk = 0;
        if (i < jb.valid2) {
            float2 v = ((const float2*)jb.src)[i];
            pk = (unsigned int)f2b(v.x) | ((unsigned int)f2b(v.y) << 16);
        }
        d32[i] = pk;
    }
}

// ---------------------------------------------------------------------------
// K0b: fp32 -> bf16 hi/lo split (x ~= hi + lo, lo = bf16(x - hi))
// ---------------------------------------------------------------------------
struct HlJob { const float* src; unsigned short* hi; unsigned short* lo; int n2; };
struct HlJobs { HlJob j[2]; };

__global__ __launch_bounds__(256) void k_cvt_hilo(HlJobs jobs) {
    HlJob jb = jobs.j[blockIdx.y];
    unsigned int* h32 = (unsigned int*)jb.hi;
    unsigned int* l32 = (unsigned int*)jb.lo;
    int stride = gridDim.x * 256;
    for (int i = blockIdx.x * 256 + threadIdx.x; i < jb.n2; i += stride) {
        float2 v = ((const float2*)jb.src)[i];
        unsigned short h0 = f2b(v.x), h1 = f2b(v.y);
        unsigned short l0 = f2b(v.x - bf2f(h0)), l1 = f2b(v.y - bf2f(h1));
        h32[i] = (unsigned int)h0 | ((unsigned int)h1 << 16);
        l32[i] = (unsigned int)l0 | ((unsigned int)l1 << 16);
    }
}

// ---------------------------------------------------------------------------
// K1: fused scores+normalize+softmax. Block per (c,i).
// ---------------------------------------------------------------------------
#define SST 37  // S LDS col stride

__global__ __launch_bounds__(256) void k_attn(
    const unsigned short* __restrict__ whi, const unsigned short* __restrict__ wlo,
    const unsigned short* __restrict__ rhi, const unsigned short* __restrict__ rlo,
    const int* __restrict__ lens, unsigned short* __restrict__ attn)
{
    int bx = blockIdx.x;
    int c = bx / NI, i = bx % NI;
    __shared__ __align__(16) unsigned short Wh[64 * 32], Wl[64 * 32];
    __shared__ __align__(16) unsigned short Rh[48 * 32], Rl[48 * 32];
    __shared__ float S[64 * SST];
    int t = threadIdx.x, lane = t & 63, wid = t >> 6;
    int lrow = lane & 15, quad = lane >> 4;
    int len = lens[c];

    int grow = lane >> 2;
    int ssw = ((lane & 3) ^ ((lane >> 3) & 3)) * 8;
    const unsigned short* garr = (wid == 0) ? whi : (wid == 1) ? wlo : (wid == 2) ? rhi : rlo;
    unsigned short* larr = (wid == 0) ? Wh : (wid == 1) ? Wl : (wid == 2) ? Rh : Rl;
    int ngroups = (wid < 2) ? 4 : 3;
    size_t gbase = (wid < 2) ? (size_t)(c * NL) * ND : (size_t)(i * NQ) * ND;

    floatx4 acc[3] = {};
    int fsw = (quad ^ ((lrow >> 1) & 3)) * 8;

    for (int kt = 0; kt < ND; kt += 32) {
        for (int j = 0; j < ngroups; ++j) {
            int row = j * 16 + grow;
            gload16(garr + gbase + (size_t)row * ND + kt + ssw, larr + j * 512 + lane * 8);
        }
        __syncthreads();
        bf16x8 ah = *(const bf16x8*)&Wh[(wid * 16 + lrow) * 32 + fsw];
        bf16x8 al = *(const bf16x8*)&Wl[(wid * 16 + lrow) * 32 + fsw];
#pragma unroll
        for (int nt = 0; nt < 3; ++nt) {
            bf16x8 bh = *(const bf16x8*)&Rh[(nt * 16 + lrow) * 32 + fsw];
            bf16x8 bl = *(const bf16x8*)&Rl[(nt * 16 + lrow) * 32 + fsw];
            acc[nt] = __builtin_amdgcn_mfma_f32_16x16x32_bf16(ah, bh, acc[nt], 0, 0, 0);
            acc[nt] = __builtin_amdgcn_mfma_f32_16x16x32_bf16(ah, bl, acc[nt], 0, 0, 0);
            acc[nt] = __builtin_amdgcn_mfma_f32_16x16x32_bf16(al, bh, acc[nt], 0, 0, 0);
        }
        __syncthreads();
    }
#pragma unroll
    for (int nt = 0; nt < 3; ++nt) {
        int q = nt * 16 + lrow;
        if (q < NQ) {
#pragma unroll
            for (int r = 0; r < 4; ++r) {
                int l = wid * 16 + quad * 4 + r;
                S[l * SST + q] = acc[nt][r];
            }
        }
    }
    __syncthreads();
    if (t < NL) {
        float lv[NQ];
        float ss = 0.f;
#pragma unroll
        for (int q = 0; q < NQ; ++q) {
            float v = S[t * SST + q];
            float x = (v >= 0.f) ? v : 0.1f * v;
            lv[q] = x;
            ss += x * x;
        }
        float inv = LAMBDA / fmaxf(sqrtf(ss), 1e-12f);
#pragma unroll
        for (int q = 0; q < NQ; ++q) S[t * SST + q] = lv[q] * inv;
    }
    __syncthreads();
    if (t < NQ) {
        int q = t;
        float m = -1e30f;
        for (int l = 0; l < len; ++l) m = fmaxf(m, S[l * SST + q]);
        float sum = 0.f;
        for (int l = 0; l < len; ++l) {
            float p = __expf(S[l * SST + q] - m);
            S[l * SST + q] = p;
            sum += p;
        }
        float inv = 1.f / sum;
        unsigned int* o = (unsigned int*)attn + ((size_t)(c * NI + i) * NQ + q) * 32;
        for (int j = 0; j < 32; ++j) {
            int l0 = 2 * j, l1 = 2 * j + 1;
            unsigned short a0 = (l0 < len) ? f2b(S[l0 * SST + q] * inv) : (unsigned short)0;
            unsigned short a1 = (l1 < len) ? f2b(S[l1 * SST + q] * inv) : (unsigned short)0;
            o[j] = (unsigned int)a0 | ((unsigned int)a1 << 16);
        }
    }
}

// ---------------------------------------------------------------------------
// K2: P_t[c][n][l64] = wrd_pad(1664xK) . W(NxK)^T, transposed scatter store.
// ---------------------------------------------------------------------------
__global__ __launch_bounds__(256, 2) void k_pgemm(
    const unsigned short* __restrict__ A, const unsigned short* __restrict__ B1,
    const unsigned short* __restrict__ B2, unsigned short* __restrict__ P1,
    unsigned short* __restrict__ P2)
{
    const int K = ND;
    int bn = blockIdx.x, bm = blockIdx.y;
    const unsigned short* B = blockIdx.z ? B2 : B1;
    unsigned short* P = blockIdx.z ? P2 : P1;
    int m0 = bm * BM, n0 = bn * BN;

    __shared__ __align__(16) unsigned short At[BM * BK];
    __shared__ __align__(16) unsigned short Bt[BN * BK];

    int t = threadIdx.x, lane = t & 63, wid = t >> 6;
    int wx = wid & 1, wy = wid >> 1;
    int lrow = lane & 15, quad = lane >> 4;
    floatx4 acc[4][4] = {};

    int srow = t >> 2, pos = t & 3;
    int ssw = (pos ^ ((srow >> 1) & 3)) * 8;
    const unsigned short* Aptr = A + (size_t)(m0 + srow) * K + ssw;
    const unsigned short* Bptr = B + (size_t)(n0 + srow) * K + ssw;
    unsigned short* Al  = &At[srow * BK + pos * 8];
    unsigned short* Al2 = &At[(srow + 64) * BK + pos * 8];
    unsigned short* Bl  = &Bt[srow * BK + pos * 8];
    unsigned short* Bl2 = &Bt[(srow + 64) * BK + pos * 8];
    int fsw = (quad ^ ((lrow >> 1) & 3)) * 8;

    for (int kt = 0; kt < K; kt += BK) {
        gload16(Aptr + kt, Al);
        gload16(Aptr + (size_t)64 * K + kt, Al2);
        gload16(Bptr + kt, Bl);
        gload16(Bptr + (size_t)64 * K + kt, Bl2);
        __syncthreads();
        bf16x8 af[4], bfr[4];
#pragma unroll
        for (int im = 0; im < 4; ++im)
            af[im] = *(const bf16x8*)&At[(wy * 64 + im * 16 + lrow) * BK + fsw];
#pragma unroll
        for (int in = 0; in < 4; ++in)
            bfr[in] = *(const bf16x8*)&Bt[(wx * 64 + in * 16 + lrow) * BK + fsw];
#pragma unroll
        for (int im = 0; im < 4; ++im)
#pragma unroll
            for (int in = 0; in < 4; ++in)
                acc[im][in] = __builtin_amdgcn_mfma_f32_16x16x32_bf16(
                    af[im], bfr[in], acc[im][in], 0, 0, 0);
        __syncthreads();
    }
#pragma unroll
    for (int im = 0; im < 4; ++im)
#pragma unroll
        for (int in = 0; in < 4; ++in) {
            int n = n0 + wx * 64 + in * 16 + lrow;
#pragma unroll
            for (int r = 0; r < 4; ++r) {
                int m = m0 + wy * 64 + im * 16 + quad * 4 + r;
                int c = m / NL, l = m - c * NL;
                if (c < NC) P[((size_t)(c * ND + n)) * 64 + l] = f2b(acc[im][in][r]);
            }
        }
}

// ---------------------------------------------------------------------------
// K3: batched K=64 dual GEMM + FiLM epilogue.
// ---------------------------------------------------------------------------
__global__ __launch_bounds__(256, 2) void k_attn_gemm(
    const unsigned short* __restrict__ attn, const unsigned short* __restrict__ Psc,
    const unsigned short* __restrict__ Psh, const float* __restrict__ bsc,
    const float* __restrict__ bsh, const float* __restrict__ rgnf,
    unsigned short* __restrict__ xbuf)
{
    int bn = blockIdx.x, bm = blockIdx.y, c = blockIdx.z;
    __shared__ __align__(16) unsigned short At[128 * 64], B1t[128 * 64], B2t[128 * 64];
    int t = threadIdx.x, lane = t & 63, wid = t >> 6;
    int wx = wid & 1, wy = wid >> 1;
    int lrow = lane & 15, quad = lane >> 4;
    int grow = lane >> 3, pos = lane & 7;

    const unsigned short* Ab  = attn + (size_t)(c * 1152 + bm * 128) * 64;
    const unsigned short* B1b = Psc + (size_t)(c * ND + bn * 128) * 64;
    const unsigned short* B2b = Psh + (size_t)(c * ND + bn * 128) * 64;
    for (int g = wid; g < 16; g += 4) {
        int row = g * 8 + grow;
        int ssw = (pos ^ (row & 7)) * 8;
        gload16(Ab + (size_t)row * 64 + ssw, &At[g * 512 + lane * 8]);
        gload16(B1b + (size_t)row * 64 + ssw, &B1t[g * 512 + lane * 8]);
        gload16(B2b + (size_t)row * 64 + ssw, &B2t[g * 512 + lane * 8]);
    }
    __syncthreads();

    floatx4 acc[4][4] = {}, acc2[4][4] = {};
#pragma unroll
    for (int kk = 0; kk < 2; ++kk) {
        int sw = ((kk * 4 + quad) ^ (lrow & 7)) * 8;
        bf16x8 af[4], b1f[4], b2f[4];
#pragma unroll
        for (int im = 0; im < 4; ++im)
            af[im] = *(const bf16x8*)&At[(wy * 64 + im * 16 + lrow) * 64 + sw];
#pragma unroll
        for (int in = 0; in < 4; ++in) {
            b1f[in] = *(const bf16x8*)&B1t[(wx * 64 + in * 16 + lrow) * 64 + sw];
            b2f[in] = *(const bf16x8*)&B2t[(wx * 64 + in * 16 + lrow) * 64 + sw];
        }
#pragma unroll
        for (int im = 0; im < 4; ++im)
#pragma unroll
            for (int in = 0; in < 4; ++in) {
                acc[im][in] = __builtin_amdgcn_mfma_f32_16x16x32_bf16(
                    af[im], b1f[in], acc[im][in], 0, 0, 0);
                acc2[im][in] = __builtin_amdgcn_mfma_f32_16x16x32_bf16(
                    af[im], b2f[in], acc2[im][in], 0, 0, 0);
            }
    }
#pragma unroll
    for (int im = 0; im < 4; ++im)
#pragma unroll
        for (int in = 0; in < 4; ++in) {
            int n = bn * 128 + wx * 64 + in * 16 + lrow;
            float b1v = bsc[n], b2v = bsh[n];
#pragma unroll
            for (int r = 0; r < 4; ++r) {
                int m = bm * 128 + wy * 64 + im * 16 + quad * 4 + r;  // < 1152
                int i = m / NQ, q = m - i * NQ;
                float sc = tanhf(acc[im][in][r] + b1v);
                float sh = acc2[im][in][r] + b2v;
                float rg = rgnf[(size_t)(i * NQ + q) * ND + n];
                xbuf[((size_t)(c * 1152 + m)) * ND + n] = f2b(rg * sc + sh);
            }
        }
}

// ---------------------------------------------------------------------------
// Main GEMM: 256x256 tile, BK=64, 8 waves, 8-phase schedule with counted vmcnt.
// LDS 128 KiB: A/B x 2 dbuf x 2 K-halves (256 rows x 32 cols bf16, 16 KB each).
// Per phase: ds_read one reg subtile + stage one half-tile (2 gload16/thread)
// + barrier + 16 MFMA (setprio-wrapped) + [even phases: vmcnt(8)] + barrier.
// Ledger: buf0 read P1-P4, restaged P3-P6 (tile+2); buf1 read P5-P8, restaged
// P7,P8,P1,P2 (tile+2). Every even-phase vmcnt(8) confirms exactly the 2
// half-tiles needed one phase later; 8 loads always in flight, never vmcnt(0).
// MODE 1: h = relu(A.B1^T + b1) (bf16).  MODE 2: out = A.B1^T + b1 + rgn
// (fp32, (i,c,q) permuted store).  XCD-grouped swizzle: 576 blocks = 8 XCDs x
// (18 bm x 4 bn); bn-siblings adjacent -> A-panel L2 reuse.
// ---------------------------------------------------------------------------
template <int MODE>
__global__ __launch_bounds__(512, 2) void k_gemm(
    const unsigned short* __restrict__ A, const unsigned short* __restrict__ B1,
    const float* __restrict__ bias1, const float* __restrict__ rgnf,
    void* __restrict__ outp)
{
    const int K = ND;
    extern __shared__ unsigned short lds[];
    unsigned short* ldsA = lds;            // 2 buf x 2 kk x 8192 elems
    unsigned short* ldsB = lds + 32768;

    int lin = blockIdx.x;
    int xcd = lin & 7;
    int kb  = lin >> 3;               // 0..71
    int bm  = xcd * 18 + (kb >> 2);   // 144 m-tiles, 18 per XCD
    int bn  = kb & 3;                 // 4 n-tiles
    int m0 = bm * 256, n0 = bn * 256;

    int t = threadIdx.x, lane = t & 63, wid = t >> 6;
    int wx = wid & 3, wy = wid >> 2;
    int lrow = lane & 15, quad = lane >> 4;
    int fsw = (quad ^ ((lrow >> 1) & 3)) * 8;

    // staging: thread t covers row = t>>2 (+128), 16B chunk (t&3) XOR-swizzled
    int srow = t >> 2;
    int schunk = ((t & 3) ^ ((t >> 3) & 3)) * 8;
    const unsigned short* Asrc = A + (size_t)(m0 + srow) * K + schunk;
    const unsigned short* Bsrc = B1 + (size_t)(n0 + srow) * K + schunk;
    unsigned short* ldA = ldsA + t * 8;
    unsigned short* ldB = ldsB + t * 8;

    floatx4 acc[8][4] = {};
    bf16x8 bfr[4];

#define SA(buf, kk, ts) { int off = (ts) * 64 + (kk) * 32; \
    unsigned short* d = ldA + (buf) * 16384 + (kk) * 8192; \
    gload16(Asrc + off, d); gload16(Asrc + (size_t)128 * K + off, d + 4096); }
#define SB(buf, kk, ts) { int off = (ts) * 64 + (kk) * 32; \
    unsigned short* d = ldB + (buf) * 16384 + (kk) * 8192; \
    gload16(Bsrc + off, d); gload16(Bsrc + (size_t)128 * K + off, d + 4096); }
#define VM8 asm volatile("s_waitcnt vmcnt(8)");
#define BARRIER { __builtin_amdgcn_s_barrier(); __builtin_amdgcn_sched_barrier(0); }

    // prologue: tile0 (buf0) both halves, tile1 (buf1) kk=0
    SA(0, 0, 0) SB(0, 0, 0) SA(0, 1, 0) SB(0, 1, 0) SA(1, 0, 1) SB(1, 0, 1)
    VM8 BARRIER

#define PH(buf, kk, mh, STAGE, WAIT) \
    { \
        const unsigned short* ab = ldsA + (buf) * 16384 + (kk) * 8192; \
        bf16x8 a0 = *(const bf16x8*)&ab[(wy * 128 + (mh) * 64 +  0 + lrow) * 32 + fsw]; \
        bf16x8 a1 = *(const bf16x8*)&ab[(wy * 128 + (mh) * 64 + 16 + lrow) * 32 + fsw]; \
        bf16x8 a2 = *(const bf16x8*)&ab[(wy * 128 + (mh) * 64 + 32 + lrow) * 32 + fsw]; \
        bf16x8 a3 = *(const bf16x8*)&ab[(wy * 128 + (mh) * 64 + 48 + lrow) * 32 + fsw]; \
        if ((mh) == 0) { \
            const unsigned short* bb = ldsB + (buf) * 16384 + (kk) * 8192; \
            bfr[0] = *(const bf16x8*)&bb[(wx * 64 +  0 + lrow) * 32 + fsw]; \
            bfr[1] = *(const bf16x8*)&bb[(wx * 64 + 16 + lrow) * 32 + fsw]; \
            bfr[2] = *(const bf16x8*)&bb[(wx * 64 + 32 + lrow) * 32 + fsw]; \
            bfr[3] = *(const bf16x8*)&bb[(wx * 64 + 48 + lrow) * 32 + fsw]; \
        } \
        STAGE \
        BARRIER \
        __builtin_amdgcn_s_setprio(1); \
        _Pragma("unroll") \
        for (int in_ = 0; in_ < 4; ++in_) { \
            acc[(mh) * 4 + 0][in_] = __builtin_amdgcn_mfma_f32_16x16x32_bf16(a0, bfr[in_], acc[(mh) * 4 + 0][in_], 0, 0, 0); \
            acc[(mh) * 4 + 1][in_] = __builtin_amdgcn_mfma_f32_16x16x32_bf16(a1, bfr[in_], acc[(mh) * 4 + 1][in_], 0, 0, 0); \
            acc[(mh) * 4 + 2][in_] = __builtin_amdgcn_mfma_f32_16x16x32_bf16(a2, bfr[in_], acc[(mh) * 4 + 2][in_], 0, 0, 0); \
            acc[(mh) * 4 + 3][in_] = __builtin_amdgcn_mfma_f32_16x16x32_bf16(a3, bfr[in_], acc[(mh) * 4 + 3][in_], 0, 0, 0); \
        } \
        __builtin_amdgcn_s_setprio(0); \
        WAIT \
        BARRIER \
    }

    for (int it = 0; it < 8; ++it) {
        int ta = 2 * it + 1;
        int tb = 2 * it + 2; if (tb > 15) tb = 15;
        int tc = 2 * it + 3; if (tc > 15) tc = 15;
        PH(0, 0, 0, SA(1, 1, ta), )        // P1
        PH(0, 0, 1, SB(1, 1, ta), VM8)     // P2
        PH(0, 1, 0, SA(0, 0, tb), )        // P3
        PH(0, 1, 1, SB(0, 0, tb), VM8)     // P4
        PH(1, 0, 0, SA(0, 1, tb), )        // P5
        PH(1, 0, 1, SB(0, 1, tb), VM8)     // P6
        PH(1, 1, 0, SA(1, 0, tc), )        // P7
        PH(1, 1, 1, SB(1, 0, tc), VM8)     // P8
    }
    asm volatile("s_waitcnt vmcnt(0)");

#undef PH
#undef SA
#undef SB
#undef VM8
#undef BARRIER

    // epilogue: C/D layout col = lane&15, row = quad*4 + reg  [m89/m91]
#pragma unroll
    for (int im = 0; im < 8; ++im) {
#pragma unroll
        for (int in = 0; in < 4; ++in) {
            int n = n0 + wx * 64 + in * 16 + lrow;
            float b1v = bias1[n];
#pragma unroll
            for (int r = 0; r < 4; ++r) {
                int m = m0 + wy * 128 + im * 16 + quad * 4 + r;
                float v = acc[im][in][r];
                if constexpr (MODE == 1) {
                    float h = v + b1v;
                    ((unsigned short*)outp)[(size_t)m * ND + n] = f2b(h > 0.f ? h : 0.f);
                } else {
                    int q = m % NQ;
                    int ci = m / NQ;
                    int i = ci % NI, c = ci / NI;
                    float rg = rgnf[(size_t)(i * NQ + q) * ND + n];
                    ((float*)outp)[((size_t)(i * NC + c) * NQ + q) * ND + n] = v + b1v + rg;
                }
            }
        }
    }
}

extern "C" void kernel_launch(void* const* d_in, const int* in_sizes, int n_in,
                              void* d_out, int out_size, void* d_ws, size_t ws_size,
                              hipStream_t stream) {
    const float* rgn     = (const float*)d_in[0];
    const float* wrd     = (const float*)d_in[2];
    const int*   lens    = (const int*)d_in[4];
    const float* w_scale = (const float*)d_in[5];
    const float* b_scale = (const float*)d_in[6];
    const float* w_shift = (const float*)d_in[7];
    const float* b_shift = (const float*)d_in[8];
    const float* w1      = (const float*)d_in[9];
    const float* b1      = (const float*)d_in[10];
    const float* w2      = (const float*)d_in[11];
    const float* b2      = (const float*)d_in[12];
    float* outf = (float*)d_out;

    // workspace layout: see previous rounds (unchanged)
    char* ws = (char*)d_ws;
    unsigned short* wsc_bf = (unsigned short*)(ws + 0);
    unsigned short* wsh_bf = (unsigned short*)(ws + 2097152);
    unsigned short* w1_bf  = (unsigned short*)(ws + 4194304);
    unsigned short* w2_bf  = (unsigned short*)(ws + 6291456);
    unsigned short* wrd_bf = (unsigned short*)(ws + 8388608);
    unsigned short* attn   = (unsigned short*)(ws + 11796480);
    unsigned short* P_sct  = (unsigned short*)(ws + 16515072);
    unsigned short* P_sht  = (unsigned short*)(ws + 20709376);
    unsigned short* wrd_hi = (unsigned short*)(ws + 24903680);
    unsigned short* wrd_lo = (unsigned short*)(ws + 28209152);
    unsigned short* rgn_hi = (unsigned short*)(ws + 31514624);
    unsigned short* rgn_lo = (unsigned short*)(ws + 33898496);
    unsigned short* hbuf   = (unsigned short*)(ws + 8388608);
    unsigned short* xbuf   = (unsigned short*)d_out;  // bf16 x inside fp32 out buf

    static int s_attr = []() {
        hipFuncSetAttribute((const void*)k_gemm<1>,
                            hipFuncAttributeMaxDynamicSharedMemorySize, 131072);
        hipFuncSetAttribute((const void*)k_gemm<2>,
                            hipFuncAttributeMaxDynamicSharedMemorySize, 131072);
        return 0;
    }();
    (void)s_attr;

    CvtJobs jobs;
    jobs.j[0] = { w_scale, wsc_bf, ND * ND / 2, ND * ND / 2 };
    jobs.j[1] = { w_shift, wsh_bf, ND * ND / 2, ND * ND / 2 };
    jobs.j[2] = { w1,      w1_bf,  ND * ND / 2, ND * ND / 2 };
    jobs.j[3] = { w2,      w2_bf,  ND * ND / 2, ND * ND / 2 };
    jobs.j[4] = { wrd,     wrd_bf, 1664 * ND / 2, NC * NL * ND / 2 };
    k_cvt<<<dim3(128, 5), 256, 0, stream>>>(jobs);

    HlJobs hjobs;
    hjobs.j[0] = { wrd, wrd_hi, wrd_lo, NC * NL * ND / 2 };
    hjobs.j[1] = { rgn, rgn_hi, rgn_lo, NI * NQ * ND / 2 };
    k_cvt_hilo<<<dim3(128, 2), 256, 0, stream>>>(hjobs);

    k_attn<<<NC * NI, 256, 0, stream>>>(wrd_hi, wrd_lo, rgn_hi, rgn_lo, lens, attn);

    k_pgemm<<<dim3(8, 13, 2), 256, 0, stream>>>(wrd_bf, wsc_bf, wsh_bf, P_sct, P_sht);

    k_attn_gemm<<<dim3(8, 9, 32), 256, 0, stream>>>(attn, P_sct, P_sht,
                                                    b_scale, b_shift, rgn, xbuf);

    // 576 blocks = 8 XCDs x 18 bm x 4 bn, decoded in-kernel
    k_gemm<1><<<576, 512, 131072, stream>>>(xbuf, w1_bf, b1, rgn, hbuf);
    k_gemm<2><<<576, 512, 131072, stream>>>(hbuf, w2_bf, b2, rgn, outf);
}

// Round 3
// 543.522 us; speedup vs baseline: 1.0056x; 1.0056x over previous
//
#include <hip/hip_runtime.h>
#include <math.h>

#define NC 32
#define NI 32
#define NL 50
#define NQ 36
#define ND 1024
#define LAMBDA 9.0f

#define BM 128
#define BN 128
#define BK 32

typedef __attribute__((ext_vector_type(8))) short bf16x8;
typedef __attribute__((ext_vector_type(4))) float floatx4;

static __device__ __forceinline__ unsigned short f2b(float f) {
    unsigned int u = __float_as_uint(f);
    unsigned int r = (u + 0x7fffu + ((u >> 16) & 1u)) >> 16;  // RNE
    return (unsigned short)r;
}
static __device__ __forceinline__ float bf2f(unsigned short u) {
    return __uint_as_float(((unsigned int)u) << 16);
}

// async global->LDS, 16B/lane; LDS dest must be wave-uniform base + lane*16
static __device__ __forceinline__ void gload16(const unsigned short* g, unsigned short* l) {
    __builtin_amdgcn_global_load_lds(
        (const __attribute__((address_space(1))) unsigned int*)g,
        (__attribute__((address_space(3))) unsigned int*)l, 16, 0, 0);
}

// ---------------------------------------------------------------------------
// K0a: fp32 -> bf16 (4 weights + zero-padded wrd)
// ---------------------------------------------------------------------------
struct CvtJob { const float* src; unsigned short* dst; int n2; int valid2; };
struct CvtJobs { CvtJob j[5]; };

__global__ __launch_bounds__(256) void k_cvt(CvtJobs jobs) {
    CvtJob jb = jobs.j[blockIdx.y];
    unsigned int* d32 = (unsigned int*)jb.dst;
    int stride = gridDim.x * 256;
    for (int i = blockIdx.x * 256 + threadIdx.x; i < jb.n2; i += stride) {
        unsigned int pk = 0;
        if (i < jb.valid2) {
            float2 v = ((const float2*)jb.src)[i];
            pk = (unsigned int)f2b(v.x) | ((unsigned int)f2b(v.y) << 16);
        }
        d32[i] = pk;
    }
}

// ---------------------------------------------------------------------------
// K0b: fp32 -> bf16 hi/lo split (x ~= hi + lo, lo = bf16(x - hi))
// ---------------------------------------------------------------------------
struct HlJob { const float* src; unsigned short* hi; unsigned short* lo; int n2; };
struct HlJobs { HlJob j[2]; };

__global__ __launch_bounds__(256) void k_cvt_hilo(HlJobs jobs) {
    HlJob jb = jobs.j[blockIdx.y];
    unsigned int* h32 = (unsigned int*)jb.hi;
    unsigned int* l32 = (unsigned int*)jb.lo;
    int stride = gridDim.x * 256;
    for (int i = blockIdx.x * 256 + threadIdx.x; i < jb.n2; i += stride) {
        float2 v = ((const float2*)jb.src)[i];
        unsigned short h0 = f2b(v.x), h1 = f2b(v.y);
        unsigned short l0 = f2b(v.x - bf2f(h0)), l1 = f2b(v.y - bf2f(h1));
        h32[i] = (unsigned int)h0 | ((unsigned int)h1 << 16);
        l32[i] = (unsigned int)l0 | ((unsigned int)l1 << 16);
    }
}

// ---------------------------------------------------------------------------
// K1: fused scores+normalize+softmax. Block per (c,i).
// ---------------------------------------------------------------------------
#define SST 37  // S LDS col stride

__global__ __launch_bounds__(256) void k_attn(
    const unsigned short* __restrict__ whi, const unsigned short* __restrict__ wlo,
    const unsigned short* __restrict__ rhi, const unsigned short* __restrict__ rlo,
    const int* __restrict__ lens, unsigned short* __restrict__ attn)
{
    int bx = blockIdx.x;
    int c = bx / NI, i = bx % NI;
    __shared__ __align__(16) unsigned short Wh[64 * 32], Wl[64 * 32];
    __shared__ __align__(16) unsigned short Rh[48 * 32], Rl[48 * 32];
    __shared__ float S[64 * SST];
    int t = threadIdx.x, lane = t & 63, wid = t >> 6;
    int lrow = lane & 15, quad = lane >> 4;
    int len = lens[c];

    int grow = lane >> 2;
    int ssw = ((lane & 3) ^ ((lane >> 3) & 3)) * 8;
    const unsigned short* garr = (wid == 0) ? whi : (wid == 1) ? wlo : (wid == 2) ? rhi : rlo;
    unsigned short* larr = (wid == 0) ? Wh : (wid == 1) ? Wl : (wid == 2) ? Rh : Rl;
    int ngroups = (wid < 2) ? 4 : 3;
    size_t gbase = (wid < 2) ? (size_t)(c * NL) * ND : (size_t)(i * NQ) * ND;

    floatx4 acc[3] = {};
    int fsw = (quad ^ ((lrow >> 1) & 3)) * 8;

    for (int kt = 0; kt < ND; kt += 32) {
        for (int j = 0; j < ngroups; ++j) {
            int row = j * 16 + grow;
            gload16(garr + gbase + (size_t)row * ND + kt + ssw, larr + j * 512 + lane * 8);
        }
        __syncthreads();
        bf16x8 ah = *(const bf16x8*)&Wh[(wid * 16 + lrow) * 32 + fsw];
        bf16x8 al = *(const bf16x8*)&Wl[(wid * 16 + lrow) * 32 + fsw];
#pragma unroll
        for (int nt = 0; nt < 3; ++nt) {
            bf16x8 bh = *(const bf16x8*)&Rh[(nt * 16 + lrow) * 32 + fsw];
            bf16x8 bl = *(const bf16x8*)&Rl[(nt * 16 + lrow) * 32 + fsw];
            acc[nt] = __builtin_amdgcn_mfma_f32_16x16x32_bf16(ah, bh, acc[nt], 0, 0, 0);
            acc[nt] = __builtin_amdgcn_mfma_f32_16x16x32_bf16(ah, bl, acc[nt], 0, 0, 0);
            acc[nt] = __builtin_amdgcn_mfma_f32_16x16x32_bf16(al, bh, acc[nt], 0, 0, 0);
        }
        __syncthreads();
    }
#pragma unroll
    for (int nt = 0; nt < 3; ++nt) {
        int q = nt * 16 + lrow;
        if (q < NQ) {
#pragma unroll
            for (int r = 0; r < 4; ++r) {
                int l = wid * 16 + quad * 4 + r;
                S[l * SST + q] = acc[nt][r];
            }
        }
    }
    __syncthreads();
    if (t < NL) {
        float lv[NQ];
        float ss = 0.f;
#pragma unroll
        for (int q = 0; q < NQ; ++q) {
            float v = S[t * SST + q];
            float x = (v >= 0.f) ? v : 0.1f * v;
            lv[q] = x;
            ss += x * x;
        }
        float inv = LAMBDA / fmaxf(sqrtf(ss), 1e-12f);
#pragma unroll
        for (int q = 0; q < NQ; ++q) S[t * SST + q] = lv[q] * inv;
    }
    __syncthreads();
    if (t < NQ) {
        int q = t;
        float m = -1e30f;
        for (int l = 0; l < len; ++l) m = fmaxf(m, S[l * SST + q]);
        float sum = 0.f;
        for (int l = 0; l < len; ++l) {
            float p = __expf(S[l * SST + q] - m);
            S[l * SST + q] = p;
            sum += p;
        }
        float inv = 1.f / sum;
        unsigned int* o = (unsigned int*)attn + ((size_t)(c * NI + i) * NQ + q) * 32;
        for (int j = 0; j < 32; ++j) {
            int l0 = 2 * j, l1 = 2 * j + 1;
            unsigned short a0 = (l0 < len) ? f2b(S[l0 * SST + q] * inv) : (unsigned short)0;
            unsigned short a1 = (l1 < len) ? f2b(S[l1 * SST + q] * inv) : (unsigned short)0;
            o[j] = (unsigned int)a0 | ((unsigned int)a1 << 16);
        }
    }
}

// ---------------------------------------------------------------------------
// K2: P_t[c][n][l64] = wrd_pad(1664xK) . W(NxK)^T, transposed scatter store.
// ---------------------------------------------------------------------------
__global__ __launch_bounds__(256, 2) void k_pgemm(
    const unsigned short* __restrict__ A, const unsigned short* __restrict__ B1,
    const unsigned short* __restrict__ B2, unsigned short* __restrict__ P1,
    unsigned short* __restrict__ P2)
{
    const int K = ND;
    int bn = blockIdx.x, bm = blockIdx.y;
    const unsigned short* B = blockIdx.z ? B2 : B1;
    unsigned short* P = blockIdx.z ? P2 : P1;
    int m0 = bm * BM, n0 = bn * BN;

    __shared__ __align__(16) unsigned short At[BM * BK];
    __shared__ __align__(16) unsigned short Bt[BN * BK];

    int t = threadIdx.x, lane = t & 63, wid = t >> 6;
    int wx = wid & 1, wy = wid >> 1;
    int lrow = lane & 15, quad = lane >> 4;
    floatx4 acc[4][4] = {};

    int srow = t >> 2, pos = t & 3;
    int ssw = (pos ^ ((srow >> 1) & 3)) * 8;
    const unsigned short* Aptr = A + (size_t)(m0 + srow) * K + ssw;
    const unsigned short* Bptr = B + (size_t)(n0 + srow) * K + ssw;
    unsigned short* Al  = &At[srow * BK + pos * 8];
    unsigned short* Al2 = &At[(srow + 64) * BK + pos * 8];
    unsigned short* Bl  = &Bt[srow * BK + pos * 8];
    unsigned short* Bl2 = &Bt[(srow + 64) * BK + pos * 8];
    int fsw = (quad ^ ((lrow >> 1) & 3)) * 8;

    for (int kt = 0; kt < K; kt += BK) {
        gload16(Aptr + kt, Al);
        gload16(Aptr + (size_t)64 * K + kt, Al2);
        gload16(Bptr + kt, Bl);
        gload16(Bptr + (size_t)64 * K + kt, Bl2);
        __syncthreads();
        bf16x8 af[4], bfr[4];
#pragma unroll
        for (int im = 0; im < 4; ++im)
            af[im] = *(const bf16x8*)&At[(wy * 64 + im * 16 + lrow) * BK + fsw];
#pragma unroll
        for (int in = 0; in < 4; ++in)
            bfr[in] = *(const bf16x8*)&Bt[(wx * 64 + in * 16 + lrow) * BK + fsw];
#pragma unroll
        for (int im = 0; im < 4; ++im)
#pragma unroll
            for (int in = 0; in < 4; ++in)
                acc[im][in] = __builtin_amdgcn_mfma_f32_16x16x32_bf16(
                    af[im], bfr[in], acc[im][in], 0, 0, 0);
        __syncthreads();
    }
#pragma unroll
    for (int im = 0; im < 4; ++im)
#pragma unroll
        for (int in = 0; in < 4; ++in) {
            int n = n0 + wx * 64 + in * 16 + lrow;
#pragma unroll
            for (int r = 0; r < 4; ++r) {
                int m = m0 + wy * 64 + im * 16 + quad * 4 + r;
                int c = m / NL, l = m - c * NL;
                if (c < NC) P[((size_t)(c * ND + n)) * 64 + l] = f2b(acc[im][in][r]);
            }
        }
}

// ---------------------------------------------------------------------------
// K3: batched K=64 dual GEMM + FiLM epilogue.
// ---------------------------------------------------------------------------
__global__ __launch_bounds__(256, 2) void k_attn_gemm(
    const unsigned short* __restrict__ attn, const unsigned short* __restrict__ Psc,
    const unsigned short* __restrict__ Psh, const float* __restrict__ bsc,
    const float* __restrict__ bsh, const float* __restrict__ rgnf,
    unsigned short* __restrict__ xbuf)
{
    int bn = blockIdx.x, bm = blockIdx.y, c = blockIdx.z;
    __shared__ __align__(16) unsigned short At[128 * 64], B1t[128 * 64], B2t[128 * 64];
    int t = threadIdx.x, lane = t & 63, wid = t >> 6;
    int wx = wid & 1, wy = wid >> 1;
    int lrow = lane & 15, quad = lane >> 4;
    int grow = lane >> 3, pos = lane & 7;

    const unsigned short* Ab  = attn + (size_t)(c * 1152 + bm * 128) * 64;
    const unsigned short* B1b = Psc + (size_t)(c * ND + bn * 128) * 64;
    const unsigned short* B2b = Psh + (size_t)(c * ND + bn * 128) * 64;
    for (int g = wid; g < 16; g += 4) {
        int row = g * 8 + grow;
        int ssw = (pos ^ (row & 7)) * 8;
        gload16(Ab + (size_t)row * 64 + ssw, &At[g * 512 + lane * 8]);
        gload16(B1b + (size_t)row * 64 + ssw, &B1t[g * 512 + lane * 8]);
        gload16(B2b + (size_t)row * 64 + ssw, &B2t[g * 512 + lane * 8]);
    }
    __syncthreads();

    floatx4 acc[4][4] = {}, acc2[4][4] = {};
#pragma unroll
    for (int kk = 0; kk < 2; ++kk) {
        int sw = ((kk * 4 + quad) ^ (lrow & 7)) * 8;
        bf16x8 af[4], b1f[4], b2f[4];
#pragma unroll
        for (int im = 0; im < 4; ++im)
            af[im] = *(const bf16x8*)&At[(wy * 64 + im * 16 + lrow) * 64 + sw];
#pragma unroll
        for (int in = 0; in < 4; ++in) {
            b1f[in] = *(const bf16x8*)&B1t[(wx * 64 + in * 16 + lrow) * 64 + sw];
            b2f[in] = *(const bf16x8*)&B2t[(wx * 64 + in * 16 + lrow) * 64 + sw];
        }
#pragma unroll
        for (int im = 0; im < 4; ++im)
#pragma unroll
            for (int in = 0; in < 4; ++in) {
                acc[im][in] = __builtin_amdgcn_mfma_f32_16x16x32_bf16(
                    af[im], b1f[in], acc[im][in], 0, 0, 0);
                acc2[im][in] = __builtin_amdgcn_mfma_f32_16x16x32_bf16(
                    af[im], b2f[in], acc2[im][in], 0, 0, 0);
            }
    }
#pragma unroll
    for (int im = 0; im < 4; ++im)
#pragma unroll
        for (int in = 0; in < 4; ++in) {
            int n = bn * 128 + wx * 64 + in * 16 + lrow;
            float b1v = bsc[n], b2v = bsh[n];
#pragma unroll
            for (int r = 0; r < 4; ++r) {
                int m = bm * 128 + wy * 64 + im * 16 + quad * 4 + r;  // < 1152
                int i = m / NQ, q = m - i * NQ;
                float sc = tanhf(acc[im][in][r] + b1v);
                float sh = acc2[im][in][r] + b2v;
                float rg = rgnf[(size_t)(i * NQ + q) * ND + n];
                xbuf[((size_t)(c * 1152 + m)) * ND + n] = f2b(rg * sc + sh);
            }
        }
}

// ---------------------------------------------------------------------------
// Main GEMM: 256x256 tile, BK=64, 8 waves, 8-phase schedule, DEEP vmcnt ledger.
// LDS 128 KiB: A/B x 2 buf x 2 kk quarter-tiles (256 rows x 32 cols, 16 KB).
// Reads: P1-2 b0kk0, P3-4 b0kk1, P5-6 b1kk0, P7-8 b1kk1 (tiles 2i, 2i+1).
// Stages (1 quarter = 2 gload16/thread per phase), each issued only after the
// region's last read's end-barrier, consumed 6-7 phases later (~1000cy > HBM):
//   P1: A(b1,kk1)<-2i+1   P2: B(b0,kk0)<-2i+2   P3: A(b0,kk0)<-2i+2
//   P4: B(b0,kk1)<-2i+2   P5: A(b0,kk1)<-2i+2   P6: B(b1,kk0)<-2i+3
//   P7: A(b1,kk0)<-2i+3   P8: B(b1,kk1)<-2i+3
// vmcnt(10) at end of even phases only: steady queue = 7 macros (14 loads),
// confirms the 2 macros (4 loads) needed by the NEXT read phase. Never 0.
// ---------------------------------------------------------------------------
template <int MODE>
__global__ __launch_bounds__(512, 2) void k_gemm(
    const unsigned short* __restrict__ A, const unsigned short* __restrict__ B1,
    const float* __restrict__ bias1, const float* __restrict__ rgnf,
    void* __restrict__ outp)
{
    const int K = ND;
    extern __shared__ unsigned short lds[];
    unsigned short* ldsA = lds;            // 2 buf x 2 kk x 8192 elems
    unsigned short* ldsB = lds + 32768;

    int lin = blockIdx.x;
    int xcd = lin & 7;
    int kb  = lin >> 3;               // 0..71
    int bm  = xcd * 18 + (kb >> 2);   // 144 m-tiles, 18 per XCD
    int bn  = kb & 3;                 // 4 n-tiles
    int m0 = bm * 256, n0 = bn * 256;

    int t = threadIdx.x, lane = t & 63, wid = t >> 6;
    int wx = wid & 3, wy = wid >> 2;
    int lrow = lane & 15, quad = lane >> 4;
    int fsw = (quad ^ ((lrow >> 1) & 3)) * 8;

    // staging: thread t covers row = t>>2 (+128), 16B chunk (t&3) XOR-swizzled
    int srow = t >> 2;
    int schunk = ((t & 3) ^ ((t >> 3) & 3)) * 8;
    const unsigned short* Asrc = A + (size_t)(m0 + srow) * K + schunk;
    const unsigned short* Bsrc = B1 + (size_t)(n0 + srow) * K + schunk;
    unsigned short* ldA = ldsA + t * 8;
    unsigned short* ldB = ldsB + t * 8;

    floatx4 acc[8][4] = {};
    bf16x8 bfr[4];

#define SA(buf, kk, ts) { int off = (ts) * 64 + (kk) * 32; \
    unsigned short* d = ldA + (buf) * 16384 + (kk) * 8192; \
    gload16(Asrc + off, d); gload16(Asrc + (size_t)128 * K + off, d + 4096); }
#define SB(buf, kk, ts) { int off = (ts) * 64 + (kk) * 32; \
    unsigned short* d = ldB + (buf) * 16384 + (kk) * 8192; \
    gload16(Bsrc + off, d); gload16(Bsrc + (size_t)128 * K + off, d + 4096); }
#define VM10 asm volatile("s_waitcnt vmcnt(10)");

    // prologue: b0<-tile0 (B00,A00,B01,A01), b1<-tile1 (B10,A10,B11);
    // A(b1,kk1)<-tile1 is staged in-loop at iter0 P1 (distance 6 to P7).
    SB(0, 0, 0) SA(0, 0, 0) SB(0, 1, 0) SA(0, 1, 0)
    SB(1, 0, 1) SA(1, 0, 1) SB(1, 1, 1)
    VM10
    __builtin_amdgcn_s_barrier();
    __builtin_amdgcn_sched_barrier(0);

#define PH(buf, kk, mh, STAGE, WAIT) \
    { \
        const unsigned short* ab = ldsA + (buf) * 16384 + (kk) * 8192; \
        bf16x8 a0 = *(const bf16x8*)&ab[(wy * 128 + (mh) * 64 +  0 + lrow) * 32 + fsw]; \
        bf16x8 a1 = *(const bf16x8*)&ab[(wy * 128 + (mh) * 64 + 16 + lrow) * 32 + fsw]; \
        bf16x8 a2 = *(const bf16x8*)&ab[(wy * 128 + (mh) * 64 + 32 + lrow) * 32 + fsw]; \
        bf16x8 a3 = *(const bf16x8*)&ab[(wy * 128 + (mh) * 64 + 48 + lrow) * 32 + fsw]; \
        if ((mh) == 0) { \
            const unsigned short* bb = ldsB + (buf) * 16384 + (kk) * 8192; \
            bfr[0] = *(const bf16x8*)&bb[(wx * 64 +  0 + lrow) * 32 + fsw]; \
            bfr[1] = *(const bf16x8*)&bb[(wx * 64 + 16 + lrow) * 32 + fsw]; \
            bfr[2] = *(const bf16x8*)&bb[(wx * 64 + 32 + lrow) * 32 + fsw]; \
            bfr[3] = *(const bf16x8*)&bb[(wx * 64 + 48 + lrow) * 32 + fsw]; \
        } \
        STAGE \
        __builtin_amdgcn_s_barrier(); \
        asm volatile("s_waitcnt lgkmcnt(0)"); \
        __builtin_amdgcn_s_setprio(1); \
        _Pragma("unroll") \
        for (int in_ = 0; in_ < 4; ++in_) { \
            acc[(mh) * 4 + 0][in_] = __builtin_amdgcn_mfma_f32_16x16x32_bf16(a0, bfr[in_], acc[(mh) * 4 + 0][in_], 0, 0, 0); \
            acc[(mh) * 4 + 1][in_] = __builtin_amdgcn_mfma_f32_16x16x32_bf16(a1, bfr[in_], acc[(mh) * 4 + 1][in_], 0, 0, 0); \
            acc[(mh) * 4 + 2][in_] = __builtin_amdgcn_mfma_f32_16x16x32_bf16(a2, bfr[in_], acc[(mh) * 4 + 2][in_], 0, 0, 0); \
            acc[(mh) * 4 + 3][in_] = __builtin_amdgcn_mfma_f32_16x16x32_bf16(a3, bfr[in_], acc[(mh) * 4 + 3][in_], 0, 0, 0); \
        } \
        __builtin_amdgcn_s_setprio(0); \
        WAIT \
        __builtin_amdgcn_s_barrier(); \
        __builtin_amdgcn_sched_barrier(0); \
    }

    for (int it = 0; it < 8; ++it) {
        int ta = 2 * it + 1;                       // always in range
        int tb = 2 * it + 2; if (tb > 15) tb = 15; // clamped junk on last iter
        int tc = 2 * it + 3; if (tc > 15) tc = 15;
        PH(0, 0, 0, SA(1, 1, ta), )        // P1
        PH(0, 0, 1, SB(0, 0, tb), VM10)    // P2
        PH(0, 1, 0, SA(0, 0, tb), )        // P3
        PH(0, 1, 1, SB(0, 1, tb), VM10)    // P4
        PH(1, 0, 0, SA(0, 1, tb), )        // P5
        PH(1, 0, 1, SB(1, 0, tc), VM10)    // P6
        PH(1, 1, 0, SA(1, 0, tc), )        // P7
        PH(1, 1, 1, SB(1, 1, tc), VM10)    // P8
    }
    asm volatile("s_waitcnt vmcnt(0)");

#undef PH
#undef SA
#undef SB
#undef VM10

    // epilogue: C/D layout col = lane&15, row = quad*4 + reg  [m89/m91]
#pragma unroll
    for (int im = 0; im < 8; ++im) {
#pragma unroll
        for (int in = 0; in < 4; ++in) {
            int n = n0 + wx * 64 + in * 16 + lrow;
            float b1v = bias1[n];
#pragma unroll
            for (int r = 0; r < 4; ++r) {
                int m = m0 + wy * 128 + im * 16 + quad * 4 + r;
                float v = acc[im][in][r];
                if constexpr (MODE == 1) {
                    float h = v + b1v;
                    ((unsigned short*)outp)[(size_t)m * ND + n] = f2b(h > 0.f ? h : 0.f);
                } else {
                    int q = m % NQ;
                    int ci = m / NQ;
                    int i = ci % NI, c = ci / NI;
                    float rg = rgnf[(size_t)(i * NQ + q) * ND + n];
                    ((float*)outp)[((size_t)(i * NC + c) * NQ + q) * ND + n] = v + b1v + rg;
                }
            }
        }
    }
}

extern "C" void kernel_launch(void* const* d_in, const int* in_sizes, int n_in,
                              void* d_out, int out_size, void* d_ws, size_t ws_size,
                              hipStream_t stream) {
    const float* rgn     = (const float*)d_in[0];
    const float* wrd     = (const float*)d_in[2];
    const int*   lens    = (const int*)d_in[4];
    const float* w_scale = (const float*)d_in[5];
    const float* b_scale = (const float*)d_in[6];
    const float* w_shift = (const float*)d_in[7];
    const float* b_shift = (const float*)d_in[8];
    const float* w1      = (const float*)d_in[9];
    const float* b1      = (const float*)d_in[10];
    const float* w2      = (const float*)d_in[11];
    const float* b2      = (const float*)d_in[12];
    float* outf = (float*)d_out;

    // workspace layout: see earlier rounds (unchanged)
    char* ws = (char*)d_ws;
    unsigned short* wsc_bf = (unsigned short*)(ws + 0);
    unsigned short* wsh_bf = (unsigned short*)(ws + 2097152);
    unsigned short* w1_bf  = (unsigned short*)(ws + 4194304);
    unsigned short* w2_bf  = (unsigned short*)(ws + 6291456);
    unsigned short* wrd_bf = (unsigned short*)(ws + 8388608);
    unsigned short* attn   = (unsigned short*)(ws + 11796480);
    unsigned short* P_sct  = (unsigned short*)(ws + 16515072);
    unsigned short* P_sht  = (unsigned short*)(ws + 20709376);
    unsigned short* wrd_hi = (unsigned short*)(ws + 24903680);
    unsigned short* wrd_lo = (unsigned short*)(ws + 28209152);
    unsigned short* rgn_hi = (unsigned short*)(ws + 31514624);
    unsigned short* rgn_lo = (unsigned short*)(ws + 33898496);
    unsigned short* hbuf   = (unsigned short*)(ws + 8388608);
    unsigned short* xbuf   = (unsigned short*)d_out;  // bf16 x inside fp32 out buf

    static int s_attr = []() {
        hipFuncSetAttribute((const void*)k_gemm<1>,
                            hipFuncAttributeMaxDynamicSharedMemorySize, 131072);
        hipFuncSetAttribute((const void*)k_gemm<2>,
                            hipFuncAttributeMaxDynamicSharedMemorySize, 131072);
        return 0;
    }();
    (void)s_attr;

    CvtJobs jobs;
    jobs.j[0] = { w_scale, wsc_bf, ND * ND / 2, ND * ND / 2 };
    jobs.j[1] = { w_shift, wsh_bf, ND * ND / 2, ND * ND / 2 };
    jobs.j[2] = { w1,      w1_bf,  ND * ND / 2, ND * ND / 2 };
    jobs.j[3] = { w2,      w2_bf,  ND * ND / 2, ND * ND / 2 };
    jobs.j[4] = { wrd,     wrd_bf, 1664 * ND / 2, NC * NL * ND / 2 };
    k_cvt<<<dim3(128, 5), 256, 0, stream>>>(jobs);

    HlJobs hjobs;
    hjobs.j[0] = { wrd, wrd_hi, wrd_lo, NC * NL * ND / 2 };
    hjobs.j[1] = { rgn, rgn_hi, rgn_lo, NI * NQ * ND / 2 };
    k_cvt_hilo<<<dim3(128, 2), 256, 0, stream>>>(hjobs);

    k_attn<<<NC * NI, 256, 0, stream>>>(wrd_hi, wrd_lo, rgn_hi, rgn_lo, lens, attn);

    k_pgemm<<<dim3(8, 13, 2), 256, 0, stream>>>(wrd_bf, wsc_bf, wsh_bf, P_sct, P_sht);

    k_attn_gemm<<<dim3(8, 9, 32), 256, 0, stream>>>(attn, P_sct, P_sht,
                                                    b_scale, b_shift, rgn, xbuf);

    // 576 blocks = 8 XCDs x 18 bm x 4 bn, decoded in-kernel
    k_gemm<1><<<576, 512, 131072, stream>>>(xbuf, w1_bf, b1, rgn, hbuf);
    k_gemm<2><<<576, 512, 131072, stream>>>(hbuf, w2_bf, b2, rgn, outf);
}

// Round 4
// 493.330 us; speedup vs baseline: 1.1079x; 1.1017x over previous
//
#include <hip/hip_runtime.h>
#include <math.h>

#define NC 32
#define NI 32
#define NL 50
#define NQ 36
#define ND 1024
#define LAMBDA 9.0f

#define BM 128
#define BN 128
#define BK 32

typedef __attribute__((ext_vector_type(8))) short bf16x8;
typedef __attribute__((ext_vector_type(4))) float floatx4;

static __device__ __forceinline__ unsigned short f2b(float f) {
    unsigned int u = __float_as_uint(f);
    unsigned int r = (u + 0x7fffu + ((u >> 16) & 1u)) >> 16;  // RNE
    return (unsigned short)r;
}
static __device__ __forceinline__ float bf2f(unsigned short u) {
    return __uint_as_float(((unsigned int)u) << 16);
}

// fast tanh: copysign(1 - 2/(e^{2|x|}+1), x); exact at 0, saturates to +-1
static __device__ __forceinline__ float ftanh(float x) {
    float ax = fabsf(x);
    float e = __expf(ax + ax);
    return copysignf(1.f - 2.f / (e + 1.f), x);
}

// async global->LDS, 16B/lane; LDS dest must be wave-uniform base + lane*16
static __device__ __forceinline__ void gload16(const unsigned short* g, unsigned short* l) {
    __builtin_amdgcn_global_load_lds(
        (const __attribute__((address_space(1))) unsigned int*)g,
        (__attribute__((address_space(3))) unsigned int*)l, 16, 0, 0);
}

// ---------------------------------------------------------------------------
// K0a: fp32 -> bf16 (4 weights + zero-padded wrd)
// ---------------------------------------------------------------------------
struct CvtJob { const float* src; unsigned short* dst; int n2; int valid2; };
struct CvtJobs { CvtJob j[5]; };

__global__ __launch_bounds__(256) void k_cvt(CvtJobs jobs) {
    CvtJob jb = jobs.j[blockIdx.y];
    unsigned int* d32 = (unsigned int*)jb.dst;
    int stride = gridDim.x * 256;
    for (int i = blockIdx.x * 256 + threadIdx.x; i < jb.n2; i += stride) {
        unsigned int pk = 0;
        if (i < jb.valid2) {
            float2 v = ((const float2*)jb.src)[i];
            pk = (unsigned int)f2b(v.x) | ((unsigned int)f2b(v.y) << 16);
        }
        d32[i] = pk;
    }
}

// ---------------------------------------------------------------------------
// K0b: fp32 -> bf16 hi/lo split (x ~= hi + lo, lo = bf16(x - hi))
// ---------------------------------------------------------------------------
struct HlJob { const float* src; unsigned short* hi; unsigned short* lo; int n2; };
struct HlJobs { HlJob j[2]; };

__global__ __launch_bounds__(256) void k_cvt_hilo(HlJobs jobs) {
    HlJob jb = jobs.j[blockIdx.y];
    unsigned int* h32 = (unsigned int*)jb.hi;
    unsigned int* l32 = (unsigned int*)jb.lo;
    int stride = gridDim.x * 256;
    for (int i = blockIdx.x * 256 + threadIdx.x; i < jb.n2; i += stride) {
        float2 v = ((const float2*)jb.src)[i];
        unsigned short h0 = f2b(v.x), h1 = f2b(v.y);
        unsigned short l0 = f2b(v.x - bf2f(h0)), l1 = f2b(v.y - bf2f(h1));
        h32[i] = (unsigned int)h0 | ((unsigned int)h1 << 16);
        l32[i] = (unsigned int)l0 | ((unsigned int)l1 << 16);
    }
}

// ---------------------------------------------------------------------------
// K1: fused scores+normalize+softmax. Block per (c,i).
// S = leaky(W.R^T) via bf16 hi/lo MFMA (fp32-class precision), L2-norm over q,
// masked softmax over l -> attn bf16 [c][i][q][l64] (zeros for l>=len).
// Post-GEMM phases parallelized 4-wide with 4-lane shuffle reductions.
// ---------------------------------------------------------------------------
#define SST 37  // S LDS col stride

__global__ __launch_bounds__(256) void k_attn(
    const unsigned short* __restrict__ whi, const unsigned short* __restrict__ wlo,
    const unsigned short* __restrict__ rhi, const unsigned short* __restrict__ rlo,
    const int* __restrict__ lens, unsigned short* __restrict__ attn)
{
    int bx = blockIdx.x;
    int c = bx / NI, i = bx % NI;
    __shared__ __align__(16) unsigned short Wh[64 * 32], Wl[64 * 32];
    __shared__ __align__(16) unsigned short Rh[48 * 32], Rl[48 * 32];
    __shared__ float S[64 * SST];
    int t = threadIdx.x, lane = t & 63, wid = t >> 6;
    int lrow = lane & 15, quad = lane >> 4;
    int len = lens[c];

    // staging: wave0->Wh, wave1->Wl, wave2->Rh, wave3->Rl
    int grow = lane >> 2;                            // row within 16-row group
    int ssw = ((lane & 3) ^ ((lane >> 3) & 3)) * 8;  // swizzled source chunk
    const unsigned short* garr = (wid == 0) ? whi : (wid == 1) ? wlo : (wid == 2) ? rhi : rlo;
    unsigned short* larr = (wid == 0) ? Wh : (wid == 1) ? Wl : (wid == 2) ? Rh : Rl;
    int ngroups = (wid < 2) ? 4 : 3;
    size_t gbase = (wid < 2) ? (size_t)(c * NL) * ND : (size_t)(i * NQ) * ND;

    floatx4 acc[3] = {};
    int fsw = (quad ^ ((lrow >> 1) & 3)) * 8;

    for (int kt = 0; kt < ND; kt += 32) {
        for (int j = 0; j < ngroups; ++j) {
            int row = j * 16 + grow;
            gload16(garr + gbase + (size_t)row * ND + kt + ssw, larr + j * 512 + lane * 8);
        }
        __syncthreads();
        bf16x8 ah = *(const bf16x8*)&Wh[(wid * 16 + lrow) * 32 + fsw];
        bf16x8 al = *(const bf16x8*)&Wl[(wid * 16 + lrow) * 32 + fsw];
#pragma unroll
        for (int nt = 0; nt < 3; ++nt) {
            bf16x8 bh = *(const bf16x8*)&Rh[(nt * 16 + lrow) * 32 + fsw];
            bf16x8 bl = *(const bf16x8*)&Rl[(nt * 16 + lrow) * 32 + fsw];
            acc[nt] = __builtin_amdgcn_mfma_f32_16x16x32_bf16(ah, bh, acc[nt], 0, 0, 0);
            acc[nt] = __builtin_amdgcn_mfma_f32_16x16x32_bf16(ah, bl, acc[nt], 0, 0, 0);
            acc[nt] = __builtin_amdgcn_mfma_f32_16x16x32_bf16(al, bh, acc[nt], 0, 0, 0);
        }
        __syncthreads();
    }
    // scatter to S: l = wid*16 + quad*4 + r, q = nt*16 + lrow
#pragma unroll
    for (int nt = 0; nt < 3; ++nt) {
        int q = nt * 16 + lrow;
        if (q < NQ) {
#pragma unroll
            for (int r = 0; r < 4; ++r) {
                int l = wid * 16 + quad * 4 + r;
                S[l * SST + q] = acc[nt][r];
            }
        }
    }
    __syncthreads();
    // leaky + L2-normalize over q, times lambda -> logits.
    // 4 lanes per l (l = t>>2); 9 q's each; 4-lane shuffle reduce of ss.
    if (t < 200) {
        int l = t >> 2, part = t & 3;
        float lv[9];
        float ss = 0.f;
#pragma unroll
        for (int jj = 0; jj < 9; ++jj) {
            int q = part * 9 + jj;
            float v = S[l * SST + q];
            float x = (v >= 0.f) ? v : 0.1f * v;
            lv[jj] = x;
            ss += x * x;
        }
        ss += __shfl_xor(ss, 1);
        ss += __shfl_xor(ss, 2);
        float inv = LAMBDA / fmaxf(sqrtf(ss), 1e-12f);
#pragma unroll
        for (int jj = 0; jj < 9; ++jj) S[l * SST + part * 9 + jj] = lv[jj] * inv;
    }
    __syncthreads();
    // masked softmax over l per q: 4 lanes per q (q = t>>2), 13 l's each;
    // S keeps logits (no overwrite) -- store pass recomputes exp for its j's.
    if (t < 144) {
        int q = t >> 2, part = t & 3;
        int ls = part * 13;
        int le = ls + 13 < len ? ls + 13 : len;
        float m = -1e30f;
        for (int l = ls; l < le; ++l) m = fmaxf(m, S[l * SST + q]);
        m = fmaxf(m, __shfl_xor(m, 1));
        m = fmaxf(m, __shfl_xor(m, 2));
        float sum = 0.f;
        for (int l = ls; l < le; ++l) sum += __expf(S[l * SST + q] - m);
        sum += __shfl_xor(sum, 1);
        sum += __shfl_xor(sum, 2);
        float inv = 1.f / sum;
        unsigned int* o = (unsigned int*)attn + ((size_t)(c * NI + i) * NQ + q) * 32;
        int jb = part * 8;
#pragma unroll
        for (int jj = 0; jj < 8; ++jj) {
            int j = jb + jj;
            int l0 = 2 * j, l1 = 2 * j + 1;
            unsigned short a0 = (l0 < len) ? f2b(__expf(S[l0 * SST + q] - m) * inv) : (unsigned short)0;
            unsigned short a1 = (l1 < len) ? f2b(__expf(S[l1 * SST + q] - m) * inv) : (unsigned short)0;
            o[j] = (unsigned int)a0 | ((unsigned int)a1 << 16);
        }
    }
}

// ---------------------------------------------------------------------------
// K2: P_t[c][n][l64] = wrd_pad(1664xK) . W(NxK)^T, transposed scatter store.
// Standard 128x128xBK32 MFMA K-loop; grid.z selects (W, dst) pair.
// ---------------------------------------------------------------------------
__global__ __launch_bounds__(256, 2) void k_pgemm(
    const unsigned short* __restrict__ A, const unsigned short* __restrict__ B1,
    const unsigned short* __restrict__ B2, unsigned short* __restrict__ P1,
    unsigned short* __restrict__ P2)
{
    const int K = ND;
    int bn = blockIdx.x, bm = blockIdx.y;
    const unsigned short* B = blockIdx.z ? B2 : B1;
    unsigned short* P = blockIdx.z ? P2 : P1;
    int m0 = bm * BM, n0 = bn * BN;

    __shared__ __align__(16) unsigned short At[BM * BK];
    __shared__ __align__(16) unsigned short Bt[BN * BK];

    int t = threadIdx.x, lane = t & 63, wid = t >> 6;
    int wx = wid & 1, wy = wid >> 1;
    int lrow = lane & 15, quad = lane >> 4;
    floatx4 acc[4][4] = {};

    int srow = t >> 2, pos = t & 3;
    int ssw = (pos ^ ((srow >> 1) & 3)) * 8;
    const unsigned short* Aptr = A + (size_t)(m0 + srow) * K + ssw;
    const unsigned short* Bptr = B + (size_t)(n0 + srow) * K + ssw;
    unsigned short* Al  = &At[srow * BK + pos * 8];
    unsigned short* Al2 = &At[(srow + 64) * BK + pos * 8];
    unsigned short* Bl  = &Bt[srow * BK + pos * 8];
    unsigned short* Bl2 = &Bt[(srow + 64) * BK + pos * 8];
    int fsw = (quad ^ ((lrow >> 1) & 3)) * 8;

    for (int kt = 0; kt < K; kt += BK) {
        gload16(Aptr + kt, Al);
        gload16(Aptr + (size_t)64 * K + kt, Al2);
        gload16(Bptr + kt, Bl);
        gload16(Bptr + (size_t)64 * K + kt, Bl2);
        __syncthreads();
        bf16x8 af[4], bfr[4];
#pragma unroll
        for (int im = 0; im < 4; ++im)
            af[im] = *(const bf16x8*)&At[(wy * 64 + im * 16 + lrow) * BK + fsw];
#pragma unroll
        for (int in = 0; in < 4; ++in)
            bfr[in] = *(const bf16x8*)&Bt[(wx * 64 + in * 16 + lrow) * BK + fsw];
#pragma unroll
        for (int im = 0; im < 4; ++im)
#pragma unroll
            for (int in = 0; in < 4; ++in)
                acc[im][in] = __builtin_amdgcn_mfma_f32_16x16x32_bf16(
                    af[im], bfr[in], acc[im][in], 0, 0, 0);
        __syncthreads();
    }
    // transposed scatter: row m -> (c = m/50, l = m%50); store P[c][n][l]
#pragma unroll
    for (int im = 0; im < 4; ++im)
#pragma unroll
        for (int in = 0; in < 4; ++in) {
            int n = n0 + wx * 64 + in * 16 + lrow;
#pragma unroll
            for (int r = 0; r < 4; ++r) {
                int m = m0 + wy * 64 + im * 16 + quad * 4 + r;
                int c = m / NL, l = m - c * NL;
                if (c < NC) P[((size_t)(c * ND + n)) * 64 + l] = f2b(acc[im][in][r]);
            }
        }
}

// ---------------------------------------------------------------------------
// K3: batched K=64 dual GEMM + FiLM epilogue (fast tanh).
// sc = tanh(attn_c . P_sc[c] + b_sc), sh = attn_c . P_sh[c] + b_sh
// x[(c,m),n] = rgn[i,q,n]*sc + sh   (bf16), m = i*NQ+q
// ---------------------------------------------------------------------------
__global__ __launch_bounds__(256, 2) void k_attn_gemm(
    const unsigned short* __restrict__ attn, const unsigned short* __restrict__ Psc,
    const unsigned short* __restrict__ Psh, const float* __restrict__ bsc,
    const float* __restrict__ bsh, const float* __restrict__ rgnf,
    unsigned short* __restrict__ xbuf)
{
    int bn = blockIdx.x, bm = blockIdx.y, c = blockIdx.z;
    __shared__ __align__(16) unsigned short At[128 * 64], B1t[128 * 64], B2t[128 * 64];
    int t = threadIdx.x, lane = t & 63, wid = t >> 6;
    int wx = wid & 1, wy = wid >> 1;
    int lrow = lane & 15, quad = lane >> 4;
    int grow = lane >> 3, pos = lane & 7;

    const unsigned short* Ab  = attn + (size_t)(c * 1152 + bm * 128) * 64;
    const unsigned short* B1b = Psc + (size_t)(c * ND + bn * 128) * 64;
    const unsigned short* B2b = Psh + (size_t)(c * ND + bn * 128) * 64;
    for (int g = wid; g < 16; g += 4) {
        int row = g * 8 + grow;
        int ssw = (pos ^ (row & 7)) * 8;
        gload16(Ab + (size_t)row * 64 + ssw, &At[g * 512 + lane * 8]);
        gload16(B1b + (size_t)row * 64 + ssw, &B1t[g * 512 + lane * 8]);
        gload16(B2b + (size_t)row * 64 + ssw, &B2t[g * 512 + lane * 8]);
    }
    __syncthreads();

    floatx4 acc[4][4] = {}, acc2[4][4] = {};
#pragma unroll
    for (int kk = 0; kk < 2; ++kk) {
        int sw = ((kk * 4 + quad) ^ (lrow & 7)) * 8;
        bf16x8 af[4], b1f[4], b2f[4];
#pragma unroll
        for (int im = 0; im < 4; ++im)
            af[im] = *(const bf16x8*)&At[(wy * 64 + im * 16 + lrow) * 64 + sw];
#pragma unroll
        for (int in = 0; in < 4; ++in) {
            b1f[in] = *(const bf16x8*)&B1t[(wx * 64 + in * 16 + lrow) * 64 + sw];
            b2f[in] = *(const bf16x8*)&B2t[(wx * 64 + in * 16 + lrow) * 64 + sw];
        }
#pragma unroll
        for (int im = 0; im < 4; ++im)
#pragma unroll
            for (int in = 0; in < 4; ++in) {
                acc[im][in] = __builtin_amdgcn_mfma_f32_16x16x32_bf16(
                    af[im], b1f[in], acc[im][in], 0, 0, 0);
                acc2[im][in] = __builtin_amdgcn_mfma_f32_16x16x32_bf16(
                    af[im], b2f[in], acc2[im][in], 0, 0, 0);
            }
    }
#pragma unroll
    for (int im = 0; im < 4; ++im)
#pragma unroll
        for (int in = 0; in < 4; ++in) {
            int n = bn * 128 + wx * 64 + in * 16 + lrow;
            float b1v = bsc[n], b2v = bsh[n];
#pragma unroll
            for (int r = 0; r < 4; ++r) {
                int m = bm * 128 + wy * 64 + im * 16 + quad * 4 + r;  // < 1152
                int i = m / NQ, q = m - i * NQ;
                float sc = ftanh(acc[im][in][r] + b1v);
                float sh = acc2[im][in][r] + b2v;
                float rg = rgnf[(size_t)(i * NQ + q) * ND + n];
                xbuf[((size_t)(c * 1152 + m)) * ND + n] = f2b(rg * sc + sh);
            }
        }
}

// ---------------------------------------------------------------------------
// Main MFMA GEMM with fused epilogues + source-swizzled LDS (R1 128^2 version).
// MODE 1: h = relu(A.B1^T + b1)  (bf16)
// MODE 2: out[(i,c,q),n] = A.B1^T + b1 + rgn  (fp32, c<->i permuted store)
// Grid: 1-D, 2304 blocks, XCD-grouped swizzle:
//   xcd = lin%8 (HW round-robin), k = lin/8
//   bm  = xcd*36 + k/8   (each XCD owns a contiguous band of 36 A-panels)
//   bn  = k%8            (8 bn-siblings adjacent -> A-panel L2 reuse x8)
// ---------------------------------------------------------------------------
template <int MODE, int MINW>
__global__ __launch_bounds__(256, MINW) void k_gemm(
    const unsigned short* __restrict__ A, const unsigned short* __restrict__ B1,
    const float* __restrict__ bias1, const float* __restrict__ rgnf,
    void* __restrict__ outp)
{
    const int K = ND;
    int lin = blockIdx.x;
    int xcd = lin & 7;
    int kb = lin >> 3;               // 0..287 within XCD
    int bm = xcd * 36 + (kb >> 3);   // 288 A-panels, 36 per XCD
    int bn = kb & 7;                 // 8 B-panels
    int m0 = bm * BM, n0 = bn * BN;

    __shared__ __align__(16) unsigned short At[BM * BK];
    __shared__ __align__(16) unsigned short Bt[BN * BK];

    int t = threadIdx.x;
    int lane = t & 63, wid = t >> 6;
    int wx = wid & 1, wy = wid >> 1;
    int lrow = lane & 15, quad = lane >> 4;

    floatx4 acc[4][4] = {};

    int srow = t >> 2, pos = t & 3;
    int ssw = (pos ^ ((srow >> 1) & 3)) * 8;
    const unsigned short* Aptr  = A  + (size_t)(m0 + srow) * K + ssw;
    const unsigned short* B1ptr = B1 + (size_t)(n0 + srow) * K + ssw;
    unsigned short* Al  = &At[srow * BK + pos * 8];
    unsigned short* Al2 = &At[(srow + 64) * BK + pos * 8];
    unsigned short* Bl  = &Bt[srow * BK + pos * 8];
    unsigned short* Bl2 = &Bt[(srow + 64) * BK + pos * 8];
    int fsw = (quad ^ ((lrow >> 1) & 3)) * 8;

    for (int kt = 0; kt < K; kt += BK) {
        gload16(Aptr + kt, Al);
        gload16(Aptr + (size_t)64 * K + kt, Al2);
        gload16(B1ptr + kt, Bl);
        gload16(B1ptr + (size_t)64 * K + kt, Bl2);
        __syncthreads();

        bf16x8 af[4], bfr[4];
#pragma unroll
        for (int im = 0; im < 4; ++im)
            af[im] = *(const bf16x8*)&At[(wy * 64 + im * 16 + lrow) * BK + fsw];
#pragma unroll
        for (int in = 0; in < 4; ++in)
            bfr[in] = *(const bf16x8*)&Bt[(wx * 64 + in * 16 + lrow) * BK + fsw];
#pragma unroll
        for (int im = 0; im < 4; ++im)
#pragma unroll
            for (int in = 0; in < 4; ++in)
                acc[im][in] = __builtin_amdgcn_mfma_f32_16x16x32_bf16(
                    af[im], bfr[in], acc[im][in], 0, 0, 0);
        __syncthreads();
    }

    // epilogue: C/D layout col = lane&15, row = quad*4 + reg  [m89/m91]
#pragma unroll
    for (int im = 0; im < 4; ++im) {
#pragma unroll
        for (int in = 0; in < 4; ++in) {
            int n = n0 + wx * 64 + in * 16 + lrow;
            float b1v = bias1[n];
#pragma unroll
            for (int r = 0; r < 4; ++r) {
                int m = m0 + wy * 64 + im * 16 + quad * 4 + r;
                int q = m % NQ;
                int ci = m / NQ;
                int i = ci % NI, c = ci / NI;
                float v = acc[im][in][r];
                if constexpr (MODE == 1) {
                    float h = v + b1v;
                    ((unsigned short*)outp)[(size_t)m * ND + n] = f2b(h > 0.f ? h : 0.f);
                } else {
                    float rg = rgnf[(size_t)(i * NQ + q) * ND + n];
                    ((float*)outp)[((size_t)(i * NC + c) * NQ + q) * ND + n] = v + b1v + rg;
                }
            }
        }
    }
}

extern "C" void kernel_launch(void* const* d_in, const int* in_sizes, int n_in,
                              void* d_out, int out_size, void* d_ws, size_t ws_size,
                              hipStream_t stream) {
    const float* rgn     = (const float*)d_in[0];
    const float* wrd     = (const float*)d_in[2];
    const int*   lens    = (const int*)d_in[4];
    const float* w_scale = (const float*)d_in[5];
    const float* b_scale = (const float*)d_in[6];
    const float* w_shift = (const float*)d_in[7];
    const float* b_shift = (const float*)d_in[8];
    const float* w1      = (const float*)d_in[9];
    const float* b1      = (const float*)d_in[10];
    const float* w2      = (const float*)d_in[11];
    const float* b2      = (const float*)d_in[12];
    float* outf = (float*)d_out;

    // workspace layout (bytes):
    //   0         wsc_bf   2,097,152
    //   2097152   wsh_bf   2,097,152
    //   4194304   w1_bf    2,097,152
    //   6291456   w2_bf    2,097,152
    //   8388608   wrd_bf   3,407,872  (1664x1024, rows>=1600 zeroed) [dead after pgemm]
    //  11796480   attn     4,718,592  [c][i][q][l64]               [dead after attn_gemm]
    //  16515072   P_sct    4,194,304  [c][n][l64]                  [dead after attn_gemm]
    //  20709376   P_sht    4,194,304                               [dead after attn_gemm]
    //  24903680   wrd_hi   3,305,472  (incl 14-row pad)            [dead after k_attn]
    //  28209152   wrd_lo   3,305,472
    //  31514624   rgn_hi   2,383,872  (incl 12-row pad)
    //  33898496   rgn_lo   2,383,872   -> scratch ends 36,282,368
    //   8388608   hbuf    75,497,472  (gemm1 output; overlaps all-dead regions)
    char* ws = (char*)d_ws;
    unsigned short* wsc_bf = (unsigned short*)(ws + 0);
    unsigned short* wsh_bf = (unsigned short*)(ws + 2097152);
    unsigned short* w1_bf  = (unsigned short*)(ws + 4194304);
    unsigned short* w2_bf  = (unsigned short*)(ws + 6291456);
    unsigned short* wrd_bf = (unsigned short*)(ws + 8388608);
    unsigned short* attn   = (unsigned short*)(ws + 11796480);
    unsigned short* P_sct  = (unsigned short*)(ws + 16515072);
    unsigned short* P_sht  = (unsigned short*)(ws + 20709376);
    unsigned short* wrd_hi = (unsigned short*)(ws + 24903680);
    unsigned short* wrd_lo = (unsigned short*)(ws + 28209152);
    unsigned short* rgn_hi = (unsigned short*)(ws + 31514624);
    unsigned short* rgn_lo = (unsigned short*)(ws + 33898496);
    unsigned short* hbuf   = (unsigned short*)(ws + 8388608);
    unsigned short* xbuf   = (unsigned short*)d_out;  // bf16 x inside fp32 out buf

    CvtJobs jobs;
    jobs.j[0] = { w_scale, wsc_bf, ND * ND / 2, ND * ND / 2 };
    jobs.j[1] = { w_shift, wsh_bf, ND * ND / 2, ND * ND / 2 };
    jobs.j[2] = { w1,      w1_bf,  ND * ND / 2, ND * ND / 2 };
    jobs.j[3] = { w2,      w2_bf,  ND * ND / 2, ND * ND / 2 };
    jobs.j[4] = { wrd,     wrd_bf, 1664 * ND / 2, NC * NL * ND / 2 };
    k_cvt<<<dim3(128, 5), 256, 0, stream>>>(jobs);

    HlJobs hjobs;
    hjobs.j[0] = { wrd, wrd_hi, wrd_lo, NC * NL * ND / 2 };
    hjobs.j[1] = { rgn, rgn_hi, rgn_lo, NI * NQ * ND / 2 };
    k_cvt_hilo<<<dim3(128, 2), 256, 0, stream>>>(hjobs);

    k_attn<<<NC * NI, 256, 0, stream>>>(wrd_hi, wrd_lo, rgn_hi, rgn_lo, lens, attn);

    k_pgemm<<<dim3(8, 13, 2), 256, 0, stream>>>(wrd_bf, wsc_bf, wsh_bf, P_sct, P_sht);

    k_attn_gemm<<<dim3(8, 9, 32), 256, 0, stream>>>(attn, P_sct, P_sht,
                                                    b_scale, b_shift, rgn, xbuf);

    // 2304 blocks, XCD-grouped swizzle (decode inside kernel)
    k_gemm<1, 2><<<2304, 256, 0, stream>>>(xbuf, w1_bf, b1, rgn, hbuf);
    k_gemm<2, 2><<<2304, 256, 0, stream>>>(hbuf, w2_bf, b2, rgn, outf);
}

// Round 5
// 435.529 us; speedup vs baseline: 1.2550x; 1.1327x over previous
//
#include <hip/hip_runtime.h>
#include <math.h>

#define NC 32
#define NI 32
#define NL 50
#define NQ 36
#define ND 1024
#define LAMBDA 9.0f

#define BM 128
#define BN 128

typedef __attribute__((ext_vector_type(8))) short bf16x8;
typedef __attribute__((ext_vector_type(4))) float floatx4;

static __device__ __forceinline__ unsigned short f2b(float f) {
    unsigned int u = __float_as_uint(f);
    unsigned int r = (u + 0x7fffu + ((u >> 16) & 1u)) >> 16;  // RNE
    return (unsigned short)r;
}
static __device__ __forceinline__ float bf2f(unsigned short u) {
    return __uint_as_float(((unsigned int)u) << 16);
}

// fast tanh: copysign(1 - 2/(e^{2|x|}+1), x); exact at 0, saturates to +-1
static __device__ __forceinline__ float ftanh(float x) {
    float ax = fabsf(x);
    float e = __expf(ax + ax);
    return copysignf(1.f - 2.f / (e + 1.f), x);
}

// async global->LDS, 16B/lane; LDS dest must be wave-uniform base + lane*16
static __device__ __forceinline__ void gload16(const unsigned short* g, unsigned short* l) {
    __builtin_amdgcn_global_load_lds(
        (const __attribute__((address_space(1))) unsigned int*)g,
        (__attribute__((address_space(3))) unsigned int*)l, 16, 0, 0);
}

// ---------------------------------------------------------------------------
// K0a: fp32 -> bf16 (4 weights + zero-padded wrd)
// ---------------------------------------------------------------------------
struct CvtJob { const float* src; unsigned short* dst; int n2; int valid2; };
struct CvtJobs { CvtJob j[5]; };

__global__ __launch_bounds__(256) void k_cvt(CvtJobs jobs) {
    CvtJob jb = jobs.j[blockIdx.y];
    unsigned int* d32 = (unsigned int*)jb.dst;
    int stride = gridDim.x * 256;
    for (int i = blockIdx.x * 256 + threadIdx.x; i < jb.n2; i += stride) {
        unsigned int pk = 0;
        if (i < jb.valid2) {
            float2 v = ((const float2*)jb.src)[i];
            pk = (unsigned int)f2b(v.x) | ((unsigned int)f2b(v.y) << 16);
        }
        d32[i] = pk;
    }
}

// ---------------------------------------------------------------------------
// K0b: fp32 -> bf16 hi/lo split (x ~= hi + lo, lo = bf16(x - hi))
// ---------------------------------------------------------------------------
struct HlJob { const float* src; unsigned short* hi; unsigned short* lo; int n2; };
struct HlJobs { HlJob j[2]; };

__global__ __launch_bounds__(256) void k_cvt_hilo(HlJobs jobs) {
    HlJob jb = jobs.j[blockIdx.y];
    unsigned int* h32 = (unsigned int*)jb.hi;
    unsigned int* l32 = (unsigned int*)jb.lo;
    int stride = gridDim.x * 256;
    for (int i = blockIdx.x * 256 + threadIdx.x; i < jb.n2; i += stride) {
        float2 v = ((const float2*)jb.src)[i];
        unsigned short h0 = f2b(v.x), h1 = f2b(v.y);
        unsigned short l0 = f2b(v.x - bf2f(h0)), l1 = f2b(v.y - bf2f(h1));
        h32[i] = (unsigned int)h0 | ((unsigned int)h1 << 16);
        l32[i] = (unsigned int)l0 | ((unsigned int)l1 << 16);
    }
}

// ---------------------------------------------------------------------------
// K1: fused scores+normalize+softmax. Block per (c,i).
// ---------------------------------------------------------------------------
#define SST 37  // S LDS col stride

__global__ __launch_bounds__(256) void k_attn(
    const unsigned short* __restrict__ whi, const unsigned short* __restrict__ wlo,
    const unsigned short* __restrict__ rhi, const unsigned short* __restrict__ rlo,
    const int* __restrict__ lens, unsigned short* __restrict__ attn)
{
    int bx = blockIdx.x;
    int c = bx / NI, i = bx % NI;
    __shared__ __align__(16) unsigned short Wh[64 * 32], Wl[64 * 32];
    __shared__ __align__(16) unsigned short Rh[48 * 32], Rl[48 * 32];
    __shared__ float S[64 * SST];
    int t = threadIdx.x, lane = t & 63, wid = t >> 6;
    int lrow = lane & 15, quad = lane >> 4;
    int len = lens[c];

    int grow = lane >> 2;
    int ssw = ((lane & 3) ^ ((lane >> 3) & 3)) * 8;
    const unsigned short* garr = (wid == 0) ? whi : (wid == 1) ? wlo : (wid == 2) ? rhi : rlo;
    unsigned short* larr = (wid == 0) ? Wh : (wid == 1) ? Wl : (wid == 2) ? Rh : Rl;
    int ngroups = (wid < 2) ? 4 : 3;
    size_t gbase = (wid < 2) ? (size_t)(c * NL) * ND : (size_t)(i * NQ) * ND;

    floatx4 acc[3] = {};
    int fsw = (quad ^ ((lrow >> 1) & 3)) * 8;

    for (int kt = 0; kt < ND; kt += 32) {
        for (int j = 0; j < ngroups; ++j) {
            int row = j * 16 + grow;
            gload16(garr + gbase + (size_t)row * ND + kt + ssw, larr + j * 512 + lane * 8);
        }
        __syncthreads();
        bf16x8 ah = *(const bf16x8*)&Wh[(wid * 16 + lrow) * 32 + fsw];
        bf16x8 al = *(const bf16x8*)&Wl[(wid * 16 + lrow) * 32 + fsw];
#pragma unroll
        for (int nt = 0; nt < 3; ++nt) {
            bf16x8 bh = *(const bf16x8*)&Rh[(nt * 16 + lrow) * 32 + fsw];
            bf16x8 bl = *(const bf16x8*)&Rl[(nt * 16 + lrow) * 32 + fsw];
            acc[nt] = __builtin_amdgcn_mfma_f32_16x16x32_bf16(ah, bh, acc[nt], 0, 0, 0);
            acc[nt] = __builtin_amdgcn_mfma_f32_16x16x32_bf16(ah, bl, acc[nt], 0, 0, 0);
            acc[nt] = __builtin_amdgcn_mfma_f32_16x16x32_bf16(al, bh, acc[nt], 0, 0, 0);
        }
        __syncthreads();
    }
#pragma unroll
    for (int nt = 0; nt < 3; ++nt) {
        int q = nt * 16 + lrow;
        if (q < NQ) {
#pragma unroll
            for (int r = 0; r < 4; ++r) {
                int l = wid * 16 + quad * 4 + r;
                S[l * SST + q] = acc[nt][r];
            }
        }
    }
    __syncthreads();
    // leaky + L2-normalize over q: 4 lanes per l, shuffle reduce
    if (t < 200) {
        int l = t >> 2, part = t & 3;
        float lv[9];
        float ss = 0.f;
#pragma unroll
        for (int jj = 0; jj < 9; ++jj) {
            int q = part * 9 + jj;
            float v = S[l * SST + q];
            float x = (v >= 0.f) ? v : 0.1f * v;
            lv[jj] = x;
            ss += x * x;
        }
        ss += __shfl_xor(ss, 1);
        ss += __shfl_xor(ss, 2);
        float inv = LAMBDA / fmaxf(sqrtf(ss), 1e-12f);
#pragma unroll
        for (int jj = 0; jj < 9; ++jj) S[l * SST + part * 9 + jj] = lv[jj] * inv;
    }
    __syncthreads();
    // masked softmax over l per q: 4 lanes per q, shuffle reduce
    if (t < 144) {
        int q = t >> 2, part = t & 3;
        int ls = part * 13;
        int le = ls + 13 < len ? ls + 13 : len;
        float m = -1e30f;
        for (int l = ls; l < le; ++l) m = fmaxf(m, S[l * SST + q]);
        m = fmaxf(m, __shfl_xor(m, 1));
        m = fmaxf(m, __shfl_xor(m, 2));
        float sum = 0.f;
        for (int l = ls; l < le; ++l) sum += __expf(S[l * SST + q] - m);
        sum += __shfl_xor(sum, 1);
        sum += __shfl_xor(sum, 2);
        float inv = 1.f / sum;
        unsigned int* o = (unsigned int*)attn + ((size_t)(c * NI + i) * NQ + q) * 32;
        int jb = part * 8;
#pragma unroll
        for (int jj = 0; jj < 8; ++jj) {
            int j = jb + jj;
            int l0 = 2 * j, l1 = 2 * j + 1;
            unsigned short a0 = (l0 < len) ? f2b(__expf(S[l0 * SST + q] - m) * inv) : (unsigned short)0;
            unsigned short a1 = (l1 < len) ? f2b(__expf(S[l1 * SST + q] - m) * inv) : (unsigned short)0;
            o[j] = (unsigned int)a0 | ((unsigned int)a1 << 16);
        }
    }
}

// ---------------------------------------------------------------------------
// K2: P_t[c][n][l64] = wrd_pad(1664xK) . W(NxK)^T, transposed scatter store.
// ---------------------------------------------------------------------------
__global__ __launch_bounds__(256, 2) void k_pgemm(
    const unsigned short* __restrict__ A, const unsigned short* __restrict__ B1,
    const unsigned short* __restrict__ B2, unsigned short* __restrict__ P1,
    unsigned short* __restrict__ P2)
{
    const int K = ND;
    const int BK = 32;
    int bn = blockIdx.x, bm = blockIdx.y;
    const unsigned short* B = blockIdx.z ? B2 : B1;
    unsigned short* P = blockIdx.z ? P2 : P1;
    int m0 = bm * BM, n0 = bn * BN;

    __shared__ __align__(16) unsigned short At[BM * 32];
    __shared__ __align__(16) unsigned short Bt[BN * 32];

    int t = threadIdx.x, lane = t & 63, wid = t >> 6;
    int wx = wid & 1, wy = wid >> 1;
    int lrow = lane & 15, quad = lane >> 4;
    floatx4 acc[4][4] = {};

    int srow = t >> 2, pos = t & 3;
    int ssw = (pos ^ ((srow >> 1) & 3)) * 8;
    const unsigned short* Aptr = A + (size_t)(m0 + srow) * K + ssw;
    const unsigned short* Bptr = B + (size_t)(n0 + srow) * K + ssw;
    unsigned short* Al  = &At[srow * BK + pos * 8];
    unsigned short* Al2 = &At[(srow + 64) * BK + pos * 8];
    unsigned short* Bl  = &Bt[srow * BK + pos * 8];
    unsigned short* Bl2 = &Bt[(srow + 64) * BK + pos * 8];
    int fsw = (quad ^ ((lrow >> 1) & 3)) * 8;

    for (int kt = 0; kt < K; kt += BK) {
        gload16(Aptr + kt, Al);
        gload16(Aptr + (size_t)64 * K + kt, Al2);
        gload16(Bptr + kt, Bl);
        gload16(Bptr + (size_t)64 * K + kt, Bl2);
        __syncthreads();
        bf16x8 af[4], bfr[4];
#pragma unroll
        for (int im = 0; im < 4; ++im)
            af[im] = *(const bf16x8*)&At[(wy * 64 + im * 16 + lrow) * BK + fsw];
#pragma unroll
        for (int in = 0; in < 4; ++in)
            bfr[in] = *(const bf16x8*)&Bt[(wx * 64 + in * 16 + lrow) * BK + fsw];
#pragma unroll
        for (int im = 0; im < 4; ++im)
#pragma unroll
            for (int in = 0; in < 4; ++in)
                acc[im][in] = __builtin_amdgcn_mfma_f32_16x16x32_bf16(
                    af[im], bfr[in], acc[im][in], 0, 0, 0);
        __syncthreads();
    }
#pragma unroll
    for (int im = 0; im < 4; ++im)
#pragma unroll
        for (int in = 0; in < 4; ++in) {
            int n = n0 + wx * 64 + in * 16 + lrow;
#pragma unroll
            for (int r = 0; r < 4; ++r) {
                int m = m0 + wy * 64 + im * 16 + quad * 4 + r;
                int c = m / NL, l = m - c * NL;
                if (c < NC) P[((size_t)(c * ND + n)) * 64 + l] = f2b(acc[im][in][r]);
            }
        }
}

// ---------------------------------------------------------------------------
// K3: batched K=64 dual GEMM + FiLM epilogue (fast tanh).
// Stores xbuf in (i,c,q) row order via LDS-packed full-line 16B stores.
// ---------------------------------------------------------------------------
__global__ __launch_bounds__(256, 2) void k_attn_gemm(
    const unsigned short* __restrict__ attn, const unsigned short* __restrict__ Psc,
    const unsigned short* __restrict__ Psh, const float* __restrict__ bsc,
    const float* __restrict__ bsh, const float* __restrict__ rgnf,
    unsigned short* __restrict__ xbuf)
{
    int bn = blockIdx.x, bm = blockIdx.y, c = blockIdx.z;
    __shared__ __align__(16) unsigned short smem3[3 * 128 * 64];
    unsigned short* At  = smem3;
    unsigned short* B1t = smem3 + 8192;
    unsigned short* B2t = smem3 + 16384;
    unsigned short* Ct  = smem3;          // 32KB epilogue overlay (At+B1t)
    int t = threadIdx.x, lane = t & 63, wid = t >> 6;
    int wx = wid & 1, wy = wid >> 1;
    int lrow = lane & 15, quad = lane >> 4;
    int grow = lane >> 3, pos = lane & 7;

    const unsigned short* Ab  = attn + (size_t)(c * 1152 + bm * 128) * 64;
    const unsigned short* B1b = Psc + (size_t)(c * ND + bn * 128) * 64;
    const unsigned short* B2b = Psh + (size_t)(c * ND + bn * 128) * 64;
    for (int g = wid; g < 16; g += 4) {
        int row = g * 8 + grow;
        int ssw = (pos ^ (row & 7)) * 8;
        gload16(Ab + (size_t)row * 64 + ssw, &At[g * 512 + lane * 8]);
        gload16(B1b + (size_t)row * 64 + ssw, &B1t[g * 512 + lane * 8]);
        gload16(B2b + (size_t)row * 64 + ssw, &B2t[g * 512 + lane * 8]);
    }
    __syncthreads();

    floatx4 acc[4][4] = {}, acc2[4][4] = {};
#pragma unroll
    for (int kk = 0; kk < 2; ++kk) {
        int sw = ((kk * 4 + quad) ^ (lrow & 7)) * 8;
        bf16x8 af[4], b1f[4], b2f[4];
#pragma unroll
        for (int im = 0; im < 4; ++im)
            af[im] = *(const bf16x8*)&At[(wy * 64 + im * 16 + lrow) * 64 + sw];
#pragma unroll
        for (int in = 0; in < 4; ++in) {
            b1f[in] = *(const bf16x8*)&B1t[(wx * 64 + in * 16 + lrow) * 64 + sw];
            b2f[in] = *(const bf16x8*)&B2t[(wx * 64 + in * 16 + lrow) * 64 + sw];
        }
#pragma unroll
        for (int im = 0; im < 4; ++im)
#pragma unroll
            for (int in = 0; in < 4; ++in) {
                acc[im][in] = __builtin_amdgcn_mfma_f32_16x16x32_bf16(
                    af[im], b1f[in], acc[im][in], 0, 0, 0);
                acc2[im][in] = __builtin_amdgcn_mfma_f32_16x16x32_bf16(
                    af[im], b2f[in], acc2[im][in], 0, 0, 0);
            }
    }
    __syncthreads();  // all LDS reads done before Ct overlay
#pragma unroll
    for (int im = 0; im < 4; ++im)
#pragma unroll
        for (int in = 0; in < 4; ++in) {
            int n = bn * 128 + wx * 64 + in * 16 + lrow;
            float b1v = bsc[n], b2v = bsh[n];
#pragma unroll
            for (int r = 0; r < 4; ++r) {
                int row = wy * 64 + im * 16 + quad * 4 + r;
                int m = bm * 128 + row;                    // < 1152, m = i*NQ+q
                int i = m / NQ, q = m - i * NQ;
                float sc = ftanh(acc[im][in][r] + b1v);
                float sh = acc2[im][in][r] + b2v;
                float rg = rgnf[(size_t)(i * NQ + q) * ND + n];
                int colc = (wx * 8 + in * 2 + (lrow >> 3)) ^ (row & 7);
                Ct[row * 128 + colc * 8 + (lrow & 7)] = f2b(rg * sc + sh);
            }
        }
    __syncthreads();
    // packed full-line stores, xbuf row' = (i*NC + c)*NQ + q
#pragma unroll
    for (int p = 0; p < 8; ++p) {
        int row = p * 16 + (t >> 4), chunk = t & 15;
        int m = bm * 128 + row;
        int i = m / NQ, q = m - i * NQ;
        size_t dr = ((size_t)(i * NC + c) * NQ + q) * ND + bn * 128 + chunk * 8;
        *(bf16x8*)&xbuf[dr] = *(const bf16x8*)&Ct[row * 128 + ((chunk ^ (row & 7)) * 8)];
    }
}

// ---------------------------------------------------------------------------
// Main MFMA GEMM, 128x128 tile, BK=64 (16 iterations), source-swizzled LDS.
// Rows of A/out are in (i,c,q) order (xbuf/hbuf layout).
// MODE 1: h = relu(A.B1^T + b1) (bf16), LDS-packed full-line stores.
// MODE 2: out[m] = A.B1^T + b1 + rgn[i,q]  (fp32, direct row store).
// XCD-grouped swizzle: 2304 blocks; bm = xcd*36 + k/8, bn = k%8.
// ---------------------------------------------------------------------------
template <int MODE, int MINW>
__global__ __launch_bounds__(256, MINW) void k_gemm(
    const unsigned short* __restrict__ A, const unsigned short* __restrict__ B1,
    const float* __restrict__ bias1, const float* __restrict__ rgnf,
    void* __restrict__ outp)
{
    const int K = ND;
    int lin = blockIdx.x;
    int xcd = lin & 7;
    int kb = lin >> 3;               // 0..287 within XCD
    int bm = xcd * 36 + (kb >> 3);   // 288 A-panels, 36 per XCD
    int bn = kb & 7;                 // 8 B-panels
    int m0 = bm * BM, n0 = bn * BN;

    __shared__ __align__(16) unsigned short smem[2 * 128 * 64];
    unsigned short* At = smem;            // [128][64]
    unsigned short* Bt = smem + 8192;     // [128][64]
    unsigned short* Ct = smem;            // 32KB epilogue overlay (MODE 1)

    int t = threadIdx.x;
    int lane = t & 63, wid = t >> 6;
    int wx = wid & 1, wy = wid >> 1;
    int lrow = lane & 15, quad = lane >> 4;

    floatx4 acc[4][4] = {};

    // staging: 256 thr x 16B = 32 rows/pass, 4 passes per matrix; source-swizzled
    int srow = t >> 3, pos = t & 7;
    int ssw = (pos ^ (srow & 7)) * 8;
    const unsigned short* Aptr  = A  + (size_t)(m0 + srow) * K + ssw;
    const unsigned short* B1ptr = B1 + (size_t)(n0 + srow) * K + ssw;
    unsigned short* ldA = At + t * 8;
    unsigned short* ldB = Bt + t * 8;

    for (int kt = 0; kt < K; kt += 64) {
#pragma unroll
        for (int p = 0; p < 4; ++p) {
            gload16(Aptr + (size_t)(p * 32) * K + kt, ldA + p * 2048);
            gload16(B1ptr + (size_t)(p * 32) * K + kt, ldB + p * 2048);
        }
        __syncthreads();
#pragma unroll
        for (int kh = 0; kh < 2; ++kh) {
            int sw = ((kh * 4 + quad) ^ (lrow & 7)) * 8;
            bf16x8 af[4], bfr[4];
#pragma unroll
            for (int im = 0; im < 4; ++im)
                af[im] = *(const bf16x8*)&At[(wy * 64 + im * 16 + lrow) * 64 + sw];
#pragma unroll
            for (int in = 0; in < 4; ++in)
                bfr[in] = *(const bf16x8*)&Bt[(wx * 64 + in * 16 + lrow) * 64 + sw];
#pragma unroll
            for (int im = 0; im < 4; ++im)
#pragma unroll
                for (int in = 0; in < 4; ++in)
                    acc[im][in] = __builtin_amdgcn_mfma_f32_16x16x32_bf16(
                        af[im], bfr[in], acc[im][in], 0, 0, 0);
        }
        __syncthreads();
    }

    // epilogue: C/D layout col = lane&15, row = quad*4 + reg  [m89/m91]
    if constexpr (MODE == 1) {
        // relu + bf16 -> Ct (swizzled), then packed full-line stores
#pragma unroll
        for (int im = 0; im < 4; ++im)
#pragma unroll
            for (int in = 0; in < 4; ++in) {
                int n = n0 + wx * 64 + in * 16 + lrow;
                float b1v = bias1[n];
#pragma unroll
                for (int r = 0; r < 4; ++r) {
                    int row = wy * 64 + im * 16 + quad * 4 + r;
                    float h = acc[im][in][r] + b1v;
                    h = h > 0.f ? h : 0.f;
                    int colc = (wx * 8 + in * 2 + (lrow >> 3)) ^ (row & 7);
                    Ct[row * 128 + colc * 8 + (lrow & 7)] = f2b(h);
                }
            }
        __syncthreads();
        unsigned short* ob = (unsigned short*)outp + (size_t)m0 * ND + n0;
#pragma unroll
        for (int p = 0; p < 8; ++p) {
            int row = p * 16 + (t >> 4), chunk = t & 15;
            *(bf16x8*)&ob[(size_t)row * ND + chunk * 8] =
                *(const bf16x8*)&Ct[row * 128 + ((chunk ^ (row & 7)) * 8)];
        }
    } else {
        // fp32 direct row store; rows are (i,c,q): i = m/1152, q = m%36
#pragma unroll
        for (int im = 0; im < 4; ++im)
#pragma unroll
            for (int in = 0; in < 4; ++in) {
                int n = n0 + wx * 64 + in * 16 + lrow;
                float b1v = bias1[n];
#pragma unroll
                for (int r = 0; r < 4; ++r) {
                    int m = m0 + wy * 64 + im * 16 + quad * 4 + r;
                    int i = m / (NC * NQ);
                    int q = m % NQ;
                    float rg = rgnf[(size_t)(i * NQ + q) * ND + n];
                    ((float*)outp)[(size_t)m * ND + n] = acc[im][in][r] + b1v + rg;
                }
            }
    }
}

extern "C" void kernel_launch(void* const* d_in, const int* in_sizes, int n_in,
                              void* d_out, int out_size, void* d_ws, size_t ws_size,
                              hipStream_t stream) {
    const float* rgn     = (const float*)d_in[0];
    const float* wrd     = (const float*)d_in[2];
    const int*   lens    = (const int*)d_in[4];
    const float* w_scale = (const float*)d_in[5];
    const float* b_scale = (const float*)d_in[6];
    const float* w_shift = (const float*)d_in[7];
    const float* b_shift = (const float*)d_in[8];
    const float* w1      = (const float*)d_in[9];
    const float* b1      = (const float*)d_in[10];
    const float* w2      = (const float*)d_in[11];
    const float* b2      = (const float*)d_in[12];
    float* outf = (float*)d_out;

    // workspace layout (bytes): see earlier rounds (unchanged)
    char* ws = (char*)d_ws;
    unsigned short* wsc_bf = (unsigned short*)(ws + 0);
    unsigned short* wsh_bf = (unsigned short*)(ws + 2097152);
    unsigned short* w1_bf  = (unsigned short*)(ws + 4194304);
    unsigned short* w2_bf  = (unsigned short*)(ws + 6291456);
    unsigned short* wrd_bf = (unsigned short*)(ws + 8388608);
    unsigned short* attn   = (unsigned short*)(ws + 11796480);
    unsigned short* P_sct  = (unsigned short*)(ws + 16515072);
    unsigned short* P_sht  = (unsigned short*)(ws + 20709376);
    unsigned short* wrd_hi = (unsigned short*)(ws + 24903680);
    unsigned short* wrd_lo = (unsigned short*)(ws + 28209152);
    unsigned short* rgn_hi = (unsigned short*)(ws + 31514624);
    unsigned short* rgn_lo = (unsigned short*)(ws + 33898496);
    unsigned short* hbuf   = (unsigned short*)(ws + 8388608);
    unsigned short* xbuf   = (unsigned short*)d_out;  // bf16 x inside fp32 out buf

    CvtJobs jobs;
    jobs.j[0] = { w_scale, wsc_bf, ND * ND / 2, ND * ND / 2 };
    jobs.j[1] = { w_shift, wsh_bf, ND * ND / 2, ND * ND / 2 };
    jobs.j[2] = { w1,      w1_bf,  ND * ND / 2, ND * ND / 2 };
    jobs.j[3] = { w2,      w2_bf,  ND * ND / 2, ND * ND / 2 };
    jobs.j[4] = { wrd,     wrd_bf, 1664 * ND / 2, NC * NL * ND / 2 };
    k_cvt<<<dim3(128, 5), 256, 0, stream>>>(jobs);

    HlJobs hjobs;
    hjobs.j[0] = { wrd, wrd_hi, wrd_lo, NC * NL * ND / 2 };
    hjobs.j[1] = { rgn, rgn_hi, rgn_lo, NI * NQ * ND / 2 };
    k_cvt_hilo<<<dim3(128, 2), 256, 0, stream>>>(hjobs);

    k_attn<<<NC * NI, 256, 0, stream>>>(wrd_hi, wrd_lo, rgn_hi, rgn_lo, lens, attn);

    k_pgemm<<<dim3(8, 13, 2), 256, 0, stream>>>(wrd_bf, wsc_bf, wsh_bf, P_sct, P_sht);

    k_attn_gemm<<<dim3(8, 9, 32), 256, 0, stream>>>(attn, P_sct, P_sht,
                                                    b_scale, b_shift, rgn, xbuf);

    // 2304 blocks, XCD-grouped swizzle (decode inside kernel)
    k_gemm<1, 2><<<2304, 256, 0, stream>>>(xbuf, w1_bf, b1, rgn, hbuf);
    k_gemm<2, 2><<<2304, 256, 0, stream>>>(hbuf, w2_bf, b2, rgn, outf);
}